// Round 21
// baseline (1846.340 us; speedup 1.0000x reference)
//
#include <hip/hip_runtime.h>

#define NN 50000
#define TT 5
#define EE 500000
#define NC 8192
#define ET (EE + NN)
#define NCH 196   // ceil(NN/256)

typedef unsigned short u16;
typedef __attribute__((ext_vector_type(8))) short bf16x8;
typedef __attribute__((ext_vector_type(4))) float f32x4;

__device__ __forceinline__ float lrelu(float x) { return x >= 0.f ? x : 0.2f * x; }
__device__ __forceinline__ float sigm(float x) { return 1.f / (1.f + expf(-x)); }
__device__ __forceinline__ float bf2f(u16 u) {
    union { unsigned int i; float f; } v; v.i = ((unsigned int)u) << 16; return v.f;
}
__device__ __forceinline__ u16 f2bf(float f) {
    unsigned int x = __float_as_uint(f);
    return (u16)((x + 0x7fffu + ((x >> 16) & 1u)) >> 16);
}
__device__ __forceinline__ ushort4 f4tobf(float4 v) {
    ushort4 u; u.x = f2bf(v.x); u.y = f2bf(v.y); u.z = f2bf(v.z); u.w = f2bf(v.w);
    return u;
}
__device__ __forceinline__ float4 bf4tof(ushort4 u) {
    return make_float4(bf2f(u.x), bf2f(u.y), bf2f(u.z), bf2f(u.w));
}

// ---------------- CSR build ----------------
__global__ void k_fill1(int* p, int n) {
    int i = blockIdx.x * 256 + threadIdx.x;
    if (i < n) p[i] = 1;
}

__global__ void k_count(const int* __restrict__ edges, int* __restrict__ cnt) {
    int i = blockIdx.x * 256 + threadIdx.x;
    if (i >= TT * EE) return;
    int t = i / EE, e = i % EE;
    int dst = edges[(size_t)t * 2 * EE + EE + e];
    atomicAdd(&cnt[t * NN + dst], 1);
}

__global__ __launch_bounds__(256) void k_scan1(const int* __restrict__ cnt,
                                               int* __restrict__ sums) {
    int t = blockIdx.x / NCH, ch = blockIdx.x % NCH;
    int i = ch * 256 + threadIdx.x;
    int v = (i < NN) ? cnt[t * NN + i] : 0;
    __shared__ int s[256];
    s[threadIdx.x] = v;
    __syncthreads();
    for (int o = 128; o > 0; o >>= 1) {
        if (threadIdx.x < o) s[threadIdx.x] += s[threadIdx.x + o];
        __syncthreads();
    }
    if (threadIdx.x == 0) sums[t * NCH + ch] = s[0];
}

__global__ __launch_bounds__(256) void k_scan2(const int* __restrict__ sums,
                                               int* __restrict__ bases,
                                               int* __restrict__ off) {
    int t = blockIdx.x;
    __shared__ int s[256];
    int v = (threadIdx.x < NCH) ? sums[t * NCH + threadIdx.x] : 0;
    s[threadIdx.x] = v;
    __syncthreads();
    for (int o = 1; o < 256; o <<= 1) {
        int tv = (threadIdx.x >= o) ? s[threadIdx.x - o] : 0;
        __syncthreads();
        s[threadIdx.x] += tv;
        __syncthreads();
    }
    if (threadIdx.x < NCH) bases[t * NCH + threadIdx.x] = s[threadIdx.x] - v;
    if (threadIdx.x == 255) off[t * (NN + 1) + NN] = s[255];
}

__global__ __launch_bounds__(256) void k_scan3(int* __restrict__ cnt,
                                               const int* __restrict__ bases,
                                               int* __restrict__ off) {
    int t = blockIdx.x / NCH, ch = blockIdx.x % NCH;
    int i = ch * 256 + threadIdx.x;
    int v = (i < NN) ? cnt[t * NN + i] : 0;
    __shared__ int s[256];
    s[threadIdx.x] = v;
    __syncthreads();
    for (int o = 1; o < 256; o <<= 1) {
        int tv = (threadIdx.x >= o) ? s[threadIdx.x - o] : 0;
        __syncthreads();
        s[threadIdx.x] += tv;
        __syncthreads();
    }
    if (i < NN) {
        int excl = bases[t * NCH + ch] + s[threadIdx.x] - v;
        off[t * (NN + 1) + i] = excl;
        cnt[t * NN + i] = excl;  // becomes fill pointer
    }
}

__global__ void k_csrfill(const int* __restrict__ edges, int* __restrict__ fil,
                          int* __restrict__ csr) {
    int i = blockIdx.x * 256 + threadIdx.x;
    if (i >= TT * ET) return;
    int t = i / ET, r = i % ET;
    int src, dst;
    if (r < EE) {
        src = edges[(size_t)t * 2 * EE + r];
        dst = edges[(size_t)t * 2 * EE + EE + r];
    } else {
        src = dst = r - EE;
    }
    int pos = atomicAdd(&fil[t * NN + dst], 1);
    csr[(size_t)t * ET + pos] = src;
}

// ---------------- prep ----------------
__global__ void k_transpose(const float* __restrict__ src, float* __restrict__ dst,
                            int R, int C) {
    int i = blockIdx.x * 256 + threadIdx.x;
    if (i >= R * C) return;
    int r = i / C, c = i % C;
    dst[c * R + r] = src[i];
}

// was/wad[l][k][hd] = sum_f W[l][k][hd*64+f] * a[l][hd][f]   (f32-exact)
__global__ void k_prep_was(const float* __restrict__ W,
                           const float* __restrict__ as_,
                           const float* __restrict__ ad_,
                           float* __restrict__ was, float* __restrict__ wad) {
    int id = blockIdx.x * 256 + threadIdx.x;
    if (id >= 2 * 64 * 4) return;
    int l = id >> 8, rem = id & 255;
    int k = rem >> 2, hd = rem & 3;
    float s = 0.f, d = 0.f;
    for (int f = 0; f < 64; ++f) {
        float w = W[(size_t)l * 16384 + k * 256 + hd * 64 + f];
        s += w * as_[l * 256 + hd * 64 + f];
        d += w * ad_[l * 256 + hd * 64 + f];
    }
    was[l * 256 + k * 4 + hd] = s;
    wad[l * 256 + k * 4 + hd] = d;
}

// Combined C^T[l][f][kk] = sum_j W[l][k][hd*64+j] * lW[l][hd*64+j][f], kk=hd*64+k
__global__ void k_prep_cmb(const float* __restrict__ W, const float* __restrict__ lW,
                           u16* __restrict__ CT) {
    int i = blockIdx.x * 256 + threadIdx.x;
    if (i >= 2 * 64 * 256) return;
    int l = i >> 14, rem = i & 16383;
    int f = rem >> 8, kk = rem & 255;
    int hd = kk >> 6, k = kk & 63;
    float s = 0.f;
    for (int j = 0; j < 64; ++j)
        s += W[(size_t)l * 16384 + k * 256 + hd * 64 + j] *
             lW[(size_t)l * 16384 + (hd * 64 + j) * 64 + f];
    CT[(size_t)l * 16384 + f * 256 + kk] = f2bf(s);
}

// cb[l][f] = sum_j gb[l][j]*lW[l][j][f] + lb[l][f]
__global__ void k_prep_cb(const float* __restrict__ gb, const float* __restrict__ lW,
                          const float* __restrict__ lb, float* __restrict__ cb) {
    int i = blockIdx.x * 256 + threadIdx.x;
    if (i >= 2 * 64) return;
    int l = i >> 6, f = i & 63;
    float s = lb[l * 64 + f];
    for (int j = 0; j < 256; ++j)
        s += gb[l * 256 + j] * lW[(size_t)l * 16384 + j * 64 + f];
    cb[l * 64 + f] = s;
}

// f32 -> bf16 bulk convert (float4 -> ushort4)
__global__ void k_f2bf4(const float* __restrict__ src, u16* __restrict__ dst, int n4) {
    int i = blockIdx.x * 256 + threadIdx.x;
    if (i >= n4) return;
    float4 f = ((const float4*)src)[i];
    ((ushort4*)dst)[i] = f4tobf(f);
}

__global__ void k_gather(const u16* __restrict__ x, const int* __restrict__ clf,
                         float* __restrict__ dst) {
    int i = blockIdx.x * 256 + threadIdx.x;
    if (i >= NC * 16) return;
    int row = i >> 4, c4 = i & 15;
    int node = clf[row];
    ushort4 u = ((const ushort4*)x)[(size_t)node * 16 + c4];
    ((float4*)dst)[row * 16 + c4] = bf4tof(u);
}

// ---------------- al/ar: x[N,64] dot was/wad[64][4] ----------------
__global__ __launch_bounds__(256) void k_alar_x(const u16* __restrict__ xb,
                                                const float* __restrict__ was,
                                                const float* __restrict__ wad,
                                                float* __restrict__ al,
                                                float* __restrict__ ar) {
    int lane = threadIdx.x & 63;
    int n = blockIdx.x * 16 + (threadIdx.x >> 6) * 4 + (lane >> 4);
    int q = lane & 15;
    ushort4 u = *(const ushort4*)&xb[(size_t)n * 64 + q * 4];
    float ps[4] = {0.f, 0.f, 0.f, 0.f};
    float pd[4] = {0.f, 0.f, 0.f, 0.f};
#pragma unroll
    for (int d = 0; d < 4; ++d) {
        u16 uv = (d == 0) ? u.x : (d == 1) ? u.y : (d == 2) ? u.z : u.w;
        float xv = bf2f(uv);
        int k = q * 4 + d;
        float4 w4 = *(const float4*)&was[k * 4];
        float4 d4 = *(const float4*)&wad[k * 4];
        ps[0] += xv * w4.x; ps[1] += xv * w4.y;
        ps[2] += xv * w4.z; ps[3] += xv * w4.w;
        pd[0] += xv * d4.x; pd[1] += xv * d4.y;
        pd[2] += xv * d4.z; pd[3] += xv * d4.w;
    }
#pragma unroll
    for (int o = 1; o < 16; o <<= 1) {
#pragma unroll
        for (int hd = 0; hd < 4; ++hd) {
            ps[hd] += __shfl_xor(ps[hd], o, 64);
            pd[hd] += __shfl_xor(pd[hd], o, 64);
        }
    }
    if (q == 0) {
        *(float4*)&al[n * 4] = make_float4(ps[0], ps[1], ps[2], ps[3]);
        *(float4*)&ar[n * 4] = make_float4(pd[0], pd[1], pd[2], pd[3]);
    }
}

// ---------------- attention aggregation over x, 2 edges/round, 4-deep pipeline ----
// (R17-verified best variant)
__global__ __launch_bounds__(256) void k_agg_x(const int* __restrict__ off,
                                               const int* __restrict__ csr,
                                               const float* __restrict__ al,
                                               const float* __restrict__ ar,
                                               const u16* __restrict__ xb,
                                               u16* __restrict__ xagg) {
    int lane = threadIdx.x & 63;
    int n = blockIdx.x * 4 + (threadIdx.x >> 6);
    int hh = lane & 3;
    int hf = lane >> 5;          // 0 = even edge of round, 1 = odd edge
    int kd = lane & 31;          // dim-pair index: dims 2kd, 2kd+1
    float ar_hh = ar[n * 4 + hh];
    int beg = off[n], end = off[n + 1];
    float den[4]  = {0.f, 0.f, 0.f, 0.f};
    float accL[4] = {0.f, 0.f, 0.f, 0.f};
    float accH[4] = {0.f, 0.f, 0.f, 0.f};

    for (int cbase = beg; cbase < end; cbase += 64) {
        int cnt = min(64, end - cbase);
        int sidx = csr[cbase + ((lane < cnt) ? lane : 0)];
        int nbat = (cnt + 15) >> 4;
        float pb[4];
#pragma unroll
        for (int b = 0; b < 4; ++b) {
            if (b < nbat) {
                int jj = b * 16 + (lane >> 2);
                int sj = __shfl(sidx, (jj < cnt) ? jj : 0, 64);
                pb[b] = expf(lrelu(al[sj * 4 + hh] + ar_hh));
            } else {
                pb[b] = 0.f;
            }
        }
        int R = (cnt + 1) >> 1;   // rounds of 2 edges

#define LDX(r, dstv)                                                         \
        {                                                                    \
            int jj_ = (r) * 2 + hf;                                          \
            int ss_ = __shfl(sidx, (jj_ < cnt) ? jj_ : 0, 64);               \
            dstv = *(const unsigned*)&xb[(size_t)ss_ * 64 + kd * 2];         \
        }
#define CONS(r, cv)                                                          \
        {                                                                    \
            int je_ = (r) * 2 + hf;                                          \
            int b_ = ((r) >> 3) & 3;                                         \
            float pbb_ = (b_ == 0) ? pb[0] : (b_ == 1) ? pb[1]               \
                        : (b_ == 2) ? pb[2] : pb[3];                         \
            float xlo_ = bf2f((u16)((cv) & 0xffffu));                        \
            float xhi_ = bf2f((u16)((cv) >> 16));                            \
            _Pragma("unroll")                                                \
            for (int hd_ = 0; hd_ < 4; ++hd_) {                              \
                float p_ = __shfl(pbb_, ((je_ & 15) << 2) | hd_, 64);        \
                p_ = (je_ < cnt) ? p_ : 0.f;                                 \
                accL[hd_] += p_ * xlo_;                                      \
                accH[hd_] += p_ * xhi_;                                      \
                den[hd_]  += p_;                                             \
            }                                                                \
        }

        unsigned c0, c1, c2, c3;
        LDX(0, c0); LDX(1, c1); LDX(2, c2); LDX(3, c3);
        for (int g = 0; g < R; g += 4) {
            unsigned n0 = 0, n1 = 0, n2 = 0, n3 = 0;
            if (g + 4 < R) {          // wave-uniform
                LDX(g + 4, n0); LDX(g + 5, n1); LDX(g + 6, n2); LDX(g + 7, n3);
            }
            CONS(g + 0, c0);
            if (g + 1 < R) CONS(g + 1, c1);
            if (g + 2 < R) CONS(g + 2, c2);
            if (g + 3 < R) CONS(g + 3, c3);
            c0 = n0; c1 = n1; c2 = n2; c3 = n3;
        }
#undef LDX
#undef CONS
    }
    // merge even/odd halves
#pragma unroll
    for (int hd = 0; hd < 4; ++hd) {
        accL[hd] += __shfl_xor(accL[hd], 32, 64);
        accH[hd] += __shfl_xor(accH[hd], 32, 64);
        den[hd]  += __shfl_xor(den[hd], 32, 64);
    }
    if (hf == 0) {
#pragma unroll
        for (int hd = 0; hd < 4; ++hd) {
            float inv = 1.f / (den[hd] + 1e-16f);
            unsigned w = (unsigned)f2bf(accL[hd] * inv) |
                         ((unsigned)f2bf(accH[hd] * inv) << 16);
            *(unsigned*)&xagg[(size_t)n * 256 + hd * 64 + kd * 2] = w;
        }
    }
}

// out[N,64](bf16) = relu(A[N,256](bf16) @ C[256,64] + cb)  -- MFMA 16x16x32
__global__ __launch_bounds__(256) void k_gemm_cmb(const u16* __restrict__ A,
                                                  const u16* __restrict__ CT,
                                                  const float* __restrict__ cb,
                                                  u16* __restrict__ out) {
    int lane = threadIdx.x & 63;
    int wid = threadIdx.x >> 6;
    int g = lane >> 4, c = lane & 15;
    int r0 = blockIdx.x * 64 + wid * 16;
    int arow = r0 + c; if (arow > NN - 1) arow = NN - 1;
    const u16* aptr = A + (size_t)arow * 256 + g * 8;
    const u16* bptr = CT + (size_t)c * 256 + g * 8;
    f32x4 acc[4];
#pragma unroll
    for (int t = 0; t < 4; ++t) acc[t] = (f32x4){0.f, 0.f, 0.f, 0.f};
#pragma unroll
    for (int ks = 0; ks < 8; ++ks) {
        bf16x8 af = *(const bf16x8*)(aptr + ks * 32);
#pragma unroll
        for (int t = 0; t < 4; ++t) {
            bf16x8 bfr = *(const bf16x8*)(bptr + t * 16 * 256 + ks * 32);
            acc[t] = __builtin_amdgcn_mfma_f32_16x16x32_bf16(af, bfr, acc[t], 0, 0, 0);
        }
    }
    int orow0 = r0 + g * 4;
#pragma unroll
    for (int t = 0; t < 4; ++t) {
        int col = t * 16 + c;
        float bv = cb[col];
#pragma unroll
        for (int j = 0; j < 4; ++j) {
            int row = orow0 + j;
            if (row < NN) out[(size_t)row * 64 + col] = f2bf(fmaxf(acc[t][j] + bv, 0.f));
        }
    }
}

// ---------------- fused LSTM1 -> LSTM2 -> FC1 -> FC2, 8 rows/wave ----------------
// Gate weights staged per-block in LDS (32-k-row chunks): L2 traffic /4, and the
// inner loop runs from LDS (weight reads 2 lanes/bank = conflict-free; xs reads
// are broadcasts).
__global__ __launch_bounds__(256) void k_lstm_fc(const float* __restrict__ seq,
                                                 const float* __restrict__ WiT1,
                                                 const float* __restrict__ WhT1,
                                                 const float* __restrict__ bb1,
                                                 const float* __restrict__ WiT2,
                                                 const float* __restrict__ WhT2,
                                                 const float* __restrict__ bb2,
                                                 const float* __restrict__ fw1,
                                                 const float* __restrict__ fb1,
                                                 const float* __restrict__ fw2,
                                                 const float* __restrict__ fb2,
                                                 float* __restrict__ out) {
    __shared__ float xs[4][8][192];
    __shared__ float wsm[32][256];
    int w = threadIdx.x >> 6, lane = threadIdx.x & 63;
    int row0 = blockIdx.x * 32 + w * 8;
    float h1[8], c1[8], h2[8], c2[8];
#pragma unroll
    for (int r = 0; r < 8; ++r) { h1[r] = 0.f; c1[r] = 0.f; h2[r] = 0.f; c2[r] = 0.f; }
    float bi1 = bb1[lane], bf1 = bb1[64 + lane], bg1 = bb1[128 + lane], bo1 = bb1[192 + lane];
    float bi2 = bb2[lane], bf2v = bb2[64 + lane], bg2 = bb2[128 + lane], bo2 = bb2[192 + lane];

    for (int st = 0; st < TT; ++st) {
        int tsn = TT - 1 - st;   // outs[::-1]
        // ---- stage LSTM1 inputs: [e1(64) | e2(64) | h1(64)]
#pragma unroll
        for (int r = 0; r < 8; ++r) {
            xs[w][r][lane]       = seq[(size_t)tsn * NC * 64 + (size_t)(row0 + r) * 64 + lane];
            xs[w][r][64 + lane]  = seq[(size_t)(TT + tsn) * NC * 64 + (size_t)(row0 + r) * 64 + lane];
            xs[w][r][128 + lane] = h1[r];
        }
        // ---- LSTM1 gates: 6 chunks of 32 k (4 from WiT1, 2 from WhT1)
        {
            float ai[8], af[8], ag[8], ao[8];
#pragma unroll
            for (int r = 0; r < 8; ++r) { ai[r] = bi1; af[r] = bf1; ag[r] = bg1; ao[r] = bo1; }
            for (int c = 0; c < 6; ++c) {
                const float* src = (c < 4) ? &WiT1[c * 32 * 256]
                                           : &WhT1[(c - 4) * 32 * 256];
                __syncthreads();   // xs staged (c==0) / previous chunk consumed
                for (int i = threadIdx.x; i < 2048; i += 256)
                    ((float4*)wsm)[i] = ((const float4*)src)[i];
                __syncthreads();
                int kbase = c * 32;
#pragma unroll
                for (int kk = 0; kk < 32; ++kk) {
                    float wi = wsm[kk][lane],       wf = wsm[kk][64 + lane];
                    float wg = wsm[kk][128 + lane], wo = wsm[kk][192 + lane];
#pragma unroll
                    for (int r = 0; r < 8; ++r) {
                        float xv = xs[w][r][kbase + kk];
                        ai[r] += xv * wi; af[r] += xv * wf;
                        ag[r] += xv * wg; ao[r] += xv * wo;
                    }
                }
            }
#pragma unroll
            for (int r = 0; r < 8; ++r) {
                c1[r] = sigm(af[r]) * c1[r] + sigm(ai[r]) * tanhf(ag[r]);
                h1[r] = sigm(ao[r]) * tanhf(c1[r]);
            }
        }
        __syncthreads();
        // ---- stage LSTM2 inputs: [h1(64) | h2(64)]
#pragma unroll
        for (int r = 0; r < 8; ++r) {
            xs[w][r][lane]      = h1[r];
            xs[w][r][64 + lane] = h2[r];
        }
        // ---- LSTM2 gates: 4 chunks of 32 k (2 from WiT2, 2 from WhT2)
        {
            float ai[8], af[8], ag[8], ao[8];
#pragma unroll
            for (int r = 0; r < 8; ++r) { ai[r] = bi2; af[r] = bf2v; ag[r] = bg2; ao[r] = bo2; }
            for (int c = 0; c < 4; ++c) {
                const float* src = (c < 2) ? &WiT2[c * 32 * 256]
                                           : &WhT2[(c - 2) * 32 * 256];
                __syncthreads();
                for (int i = threadIdx.x; i < 2048; i += 256)
                    ((float4*)wsm)[i] = ((const float4*)src)[i];
                __syncthreads();
                int kbase = c * 32;
#pragma unroll
                for (int kk = 0; kk < 32; ++kk) {
                    float wi = wsm[kk][lane],       wf = wsm[kk][64 + lane];
                    float wg = wsm[kk][128 + lane], wo = wsm[kk][192 + lane];
#pragma unroll
                    for (int r = 0; r < 8; ++r) {
                        float xv = xs[w][r][kbase + kk];
                        ai[r] += xv * wi; af[r] += xv * wf;
                        ag[r] += xv * wg; ao[r] += xv * wo;
                    }
                }
            }
#pragma unroll
            for (int r = 0; r < 8; ++r) {
                c2[r] = sigm(af[r]) * c2[r] + sigm(ai[r]) * tanhf(ag[r]);
                h2[r] = sigm(ao[r]) * tanhf(c2[r]);
            }
        }
        __syncthreads();
    }
    // ---- FC head: z = [h1 | h2]
#pragma unroll
    for (int r = 0; r < 8; ++r) {
        xs[w][r][lane]      = h1[r];
        xs[w][r][64 + lane] = h2[r];
    }
    __syncthreads();
    float acc[8];
#pragma unroll
    for (int r = 0; r < 8; ++r) acc[r] = fb1[lane];
    for (int k = 0; k < 128; ++k) {
        float wv = fw1[k * 64 + lane];
#pragma unroll
        for (int r = 0; r < 8; ++r) acc[r] += xs[w][r][k] * wv;
    }
    float w20 = fw2[lane * 2], w21 = fw2[lane * 2 + 1];
#pragma unroll
    for (int r = 0; r < 8; ++r) {
        float rr = fmaxf(acc[r], 0.f);
        float t0 = rr * w20;
        float t1 = rr * w21;
#pragma unroll
        for (int o = 32; o >= 1; o >>= 1) {
            t0 += __shfl_xor(t0, o, 64);
            t1 += __shfl_xor(t1, o, 64);
        }
        if (lane == 0) {
            out[(row0 + r) * 2]     = fmaxf(t0 + fb2[0], 0.f);
            out[(row0 + r) * 2 + 1] = fmaxf(t1 + fb2[1], 0.f);
        }
    }
}

extern "C" void kernel_launch(void* const* d_in, const int* in_sizes, int n_in,
                              void* d_out, int out_size, void* d_ws, size_t ws_size,
                              hipStream_t stream) {
    const float* emb  = (const float*)d_in[0];
    const float* g1W  = (const float*)d_in[1];
    const float* g1as = (const float*)d_in[2];
    const float* g1ad = (const float*)d_in[3];
    const float* g1b  = (const float*)d_in[4];
    const float* l1W  = (const float*)d_in[5];
    const float* l1b  = (const float*)d_in[6];
    const float* g2W  = (const float*)d_in[7];
    const float* g2as = (const float*)d_in[8];
    const float* g2ad = (const float*)d_in[9];
    const float* g2b  = (const float*)d_in[10];
    const float* l2W  = (const float*)d_in[11];
    const float* l2b  = (const float*)d_in[12];
    const float* Wi1  = (const float*)d_in[13];
    const float* Wh1  = (const float*)d_in[14];
    const float* b1   = (const float*)d_in[15];
    const float* Wi2  = (const float*)d_in[16];
    const float* Wh2  = (const float*)d_in[17];
    const float* b2   = (const float*)d_in[18];
    const float* fc1W = (const float*)d_in[19];
    const float* fc1b = (const float*)d_in[20];
    const float* fc2W = (const float*)d_in[21];
    const float* fc2b = (const float*)d_in[22];
    const int* edges = (const int*)d_in[23];
    const int* clf   = (const int*)d_in[27];

    char* ws = (char*)d_ws;
    size_t woff = 0;
    auto alloc = [&](size_t bytes) -> void* {
        void* p = ws + woff;
        woff += (bytes + 255) & ~(size_t)255;
        return p;
    };
    int* csr_off  = (int*)alloc((size_t)TT * (NN + 1) * 4);
    int* csr_fil  = (int*)alloc((size_t)TT * NN * 4);
    int* csr_src  = (int*)alloc((size_t)TT * ET * 4);
    int* scan_sum = (int*)alloc((size_t)TT * NCH * 4);
    int* scan_bas = (int*)alloc((size_t)TT * NCH * 4);
    u16* embb     = (u16*)alloc((size_t)TT * NN * 64 * 2);
    u16* xbuf     = (u16*)alloc((size_t)NN * 64 * 2);
    u16* xaggb    = (u16*)alloc((size_t)NN * 256 * 2);
    float* albuf  = (float*)alloc((size_t)NN * 4 * 4);
    float* arbuf  = (float*)alloc((size_t)NN * 4 * 4);
    float* seq    = (float*)alloc((size_t)2 * TT * NC * 64 * 4);
    float* WiT1   = (float*)alloc(128 * 256 * 4);
    float* WhT1   = (float*)alloc(64 * 256 * 4);
    float* WiT2   = (float*)alloc(64 * 256 * 4);
    float* WhT2   = (float*)alloc(64 * 256 * 4);
    u16* CT1      = (u16*)alloc((size_t)2 * 64 * 256 * 2);   // [L][64][256] bf16
    u16* CT2      = (u16*)alloc((size_t)2 * 64 * 256 * 2);
    float* cb1    = (float*)alloc((size_t)2 * 64 * 4);
    float* cb2    = (float*)alloc((size_t)2 * 64 * 4);
    float* wasb1  = (float*)alloc((size_t)2 * 64 * 4 * 4);   // [L][64][4]
    float* wadb1  = (float*)alloc((size_t)2 * 64 * 4 * 4);
    float* wasb2  = (float*)alloc((size_t)2 * 64 * 4 * 4);
    float* wadb2  = (float*)alloc((size_t)2 * 64 * 4 * 4);

    // CSR build (per snapshot, includes self-loops)
    k_fill1<<<(TT * NN + 255) / 256, 256, 0, stream>>>(csr_fil, TT * NN);
    k_count<<<(TT * EE + 255) / 256, 256, 0, stream>>>(edges, csr_fil);
    k_scan1<<<TT * NCH, 256, 0, stream>>>(csr_fil, scan_sum);
    k_scan2<<<TT, 256, 0, stream>>>(scan_sum, scan_bas, csr_off);
    k_scan3<<<TT * NCH, 256, 0, stream>>>(csr_fil, scan_bas, csr_off);
    k_csrfill<<<(TT * ET + 255) / 256, 256, 0, stream>>>(edges, csr_fil, csr_src);

    // weight preps
    k_transpose<<<(256 * 128 + 255) / 256, 256, 0, stream>>>(Wi1, WiT1, 256, 128);
    k_transpose<<<(256 * 64 + 255) / 256, 256, 0, stream>>>(Wh1, WhT1, 256, 64);
    k_transpose<<<(256 * 64 + 255) / 256, 256, 0, stream>>>(Wi2, WiT2, 256, 64);
    k_transpose<<<(256 * 64 + 255) / 256, 256, 0, stream>>>(Wh2, WhT2, 256, 64);
    k_prep_was<<<2, 256, 0, stream>>>(g1W, g1as, g1ad, wasb1, wadb1);
    k_prep_was<<<2, 256, 0, stream>>>(g2W, g2as, g2ad, wasb2, wadb2);
    k_prep_cmb<<<(2 * 64 * 256 + 255) / 256, 256, 0, stream>>>(g1W, l1W, CT1);
    k_prep_cmb<<<(2 * 64 * 256 + 255) / 256, 256, 0, stream>>>(g2W, l2W, CT2);
    k_prep_cb<<<1, 256, 0, stream>>>(g1b, l1W, l1b, cb1);
    k_prep_cb<<<1, 256, 0, stream>>>(g2b, l2W, l2b, cb2);
    // emb -> bf16
    k_f2bf4<<<(TT * NN * 16 + 255) / 256, 256, 0, stream>>>(emb, embb, TT * NN * 16);

    for (int s = 0; s < 2; ++s) {
        const float* was = s ? wasb2 : wasb1;
        const float* wad = s ? wadb2 : wadb1;
        const u16* CT    = s ? CT2 : CT1;
        const float* cbp = s ? cb2 : cb1;
        for (int t = 0; t < TT; ++t) {
            for (int l = 0; l < 2; ++l) {
                const u16* xin = (l == 0) ? (embb + (size_t)t * NN * 64) : xbuf;
                k_alar_x<<<NN / 16, 256, 0, stream>>>(
                    xin, was + l * 256, wad + l * 256, albuf, arbuf);
                k_agg_x<<<NN / 4, 256, 0, stream>>>(
                    csr_off + (size_t)t * (NN + 1), csr_src + (size_t)t * ET,
                    albuf, arbuf, xin, xaggb);
                k_gemm_cmb<<<(NN + 63) / 64, 256, 0, stream>>>(
                    xaggb, CT + (size_t)l * 16384, cbp + l * 64, xbuf);
            }
            k_gather<<<(NC * 16 + 255) / 256, 256, 0, stream>>>(
                xbuf, clf, seq + ((size_t)s * TT + t) * NC * 64);
        }
    }

    // fused LSTM1+LSTM2+FC, 8 rows/wave, LDS-staged weights
    k_lstm_fc<<<NC / 32, 256, 0, stream>>>(
        seq, WiT1, WhT1, b1, WiT2, WhT2, b2,
        fc1W, fc1b, fc2W, fc2b, (float*)d_out);
}

// Round 24
// 1790.196 us; speedup vs baseline: 1.0314x; 1.0314x over previous
//
#include <hip/hip_runtime.h>

#define NN 50000
#define TT 5
#define EE 500000
#define NC 8192
#define ET (EE + NN)
#define NCH 196   // ceil(NN/256)

typedef unsigned short u16;
typedef __attribute__((ext_vector_type(8))) short bf16x8;
typedef __attribute__((ext_vector_type(4))) float f32x4;

__device__ __forceinline__ float lrelu(float x) { return x >= 0.f ? x : 0.2f * x; }
__device__ __forceinline__ float sigm(float x) { return 1.f / (1.f + expf(-x)); }
__device__ __forceinline__ float bf2f(u16 u) {
    union { unsigned int i; float f; } v; v.i = ((unsigned int)u) << 16; return v.f;
}
__device__ __forceinline__ u16 f2bf(float f) {
    unsigned int x = __float_as_uint(f);
    return (u16)((x + 0x7fffu + ((x >> 16) & 1u)) >> 16);
}
__device__ __forceinline__ ushort4 f4tobf(float4 v) {
    ushort4 u; u.x = f2bf(v.x); u.y = f2bf(v.y); u.z = f2bf(v.z); u.w = f2bf(v.w);
    return u;
}
__device__ __forceinline__ float4 bf4tof(ushort4 u) {
    return make_float4(bf2f(u.x), bf2f(u.y), bf2f(u.z), bf2f(u.w));
}

// ---------------- CSR build ----------------
__global__ void k_fill1(int* p, int n) {
    int i = blockIdx.x * 256 + threadIdx.x;
    if (i < n) p[i] = 1;
}

__global__ void k_count(const int* __restrict__ edges, int* __restrict__ cnt) {
    int i = blockIdx.x * 256 + threadIdx.x;
    if (i >= TT * EE) return;
    int t = i / EE, e = i % EE;
    int dst = edges[(size_t)t * 2 * EE + EE + e];
    atomicAdd(&cnt[t * NN + dst], 1);
}

__global__ __launch_bounds__(256) void k_scan1(const int* __restrict__ cnt,
                                               int* __restrict__ sums) {
    int t = blockIdx.x / NCH, ch = blockIdx.x % NCH;
    int i = ch * 256 + threadIdx.x;
    int v = (i < NN) ? cnt[t * NN + i] : 0;
    __shared__ int s[256];
    s[threadIdx.x] = v;
    __syncthreads();
    for (int o = 128; o > 0; o >>= 1) {
        if (threadIdx.x < o) s[threadIdx.x] += s[threadIdx.x + o];
        __syncthreads();
    }
    if (threadIdx.x == 0) sums[t * NCH + ch] = s[0];
}

__global__ __launch_bounds__(256) void k_scan2(const int* __restrict__ sums,
                                               int* __restrict__ bases,
                                               int* __restrict__ off) {
    int t = blockIdx.x;
    __shared__ int s[256];
    int v = (threadIdx.x < NCH) ? sums[t * NCH + threadIdx.x] : 0;
    s[threadIdx.x] = v;
    __syncthreads();
    for (int o = 1; o < 256; o <<= 1) {
        int tv = (threadIdx.x >= o) ? s[threadIdx.x - o] : 0;
        __syncthreads();
        s[threadIdx.x] += tv;
        __syncthreads();
    }
    if (threadIdx.x < NCH) bases[t * NCH + threadIdx.x] = s[threadIdx.x] - v;
    if (threadIdx.x == 255) off[t * (NN + 1) + NN] = s[255];
}

__global__ __launch_bounds__(256) void k_scan3(int* __restrict__ cnt,
                                               const int* __restrict__ bases,
                                               int* __restrict__ off) {
    int t = blockIdx.x / NCH, ch = blockIdx.x % NCH;
    int i = ch * 256 + threadIdx.x;
    int v = (i < NN) ? cnt[t * NN + i] : 0;
    __shared__ int s[256];
    s[threadIdx.x] = v;
    __syncthreads();
    for (int o = 1; o < 256; o <<= 1) {
        int tv = (threadIdx.x >= o) ? s[threadIdx.x - o] : 0;
        __syncthreads();
        s[threadIdx.x] += tv;
        __syncthreads();
    }
    if (i < NN) {
        int excl = bases[t * NCH + ch] + s[threadIdx.x] - v;
        off[t * (NN + 1) + i] = excl;
        cnt[t * NN + i] = excl;  // becomes fill pointer
    }
}

__global__ void k_csrfill(const int* __restrict__ edges, int* __restrict__ fil,
                          int* __restrict__ csr) {
    int i = blockIdx.x * 256 + threadIdx.x;
    if (i >= TT * ET) return;
    int t = i / ET, r = i % ET;
    int src, dst;
    if (r < EE) {
        src = edges[(size_t)t * 2 * EE + r];
        dst = edges[(size_t)t * 2 * EE + EE + r];
    } else {
        src = dst = r - EE;
    }
    int pos = atomicAdd(&fil[t * NN + dst], 1);
    csr[(size_t)t * ET + pos] = src;
}

// ---------------- prep ----------------
__global__ void k_transpose(const float* __restrict__ src, float* __restrict__ dst,
                            int R, int C) {
    int i = blockIdx.x * 256 + threadIdx.x;
    if (i >= R * C) return;
    int r = i / C, c = i % C;
    dst[c * R + r] = src[i];
}

// Wi1 [256][128] f32 -> bf16 (already gate-major, k-contiguous = MFMA B format)
__global__ void k_prep_wi1(const float* __restrict__ W, u16* __restrict__ Wb) {
    int i = blockIdx.x * 256 + threadIdx.x;
    if (i >= 256 * 128) return;
    Wb[i] = f2bf(W[i]);
}

// was/wad[l][k][hd] = sum_f W[l][k][hd*64+f] * a[l][hd][f]   (f32-exact)
__global__ void k_prep_was(const float* __restrict__ W,
                           const float* __restrict__ as_,
                           const float* __restrict__ ad_,
                           float* __restrict__ was, float* __restrict__ wad) {
    int id = blockIdx.x * 256 + threadIdx.x;
    if (id >= 2 * 64 * 4) return;
    int l = id >> 8, rem = id & 255;
    int k = rem >> 2, hd = rem & 3;
    float s = 0.f, d = 0.f;
    for (int f = 0; f < 64; ++f) {
        float w = W[(size_t)l * 16384 + k * 256 + hd * 64 + f];
        s += w * as_[l * 256 + hd * 64 + f];
        d += w * ad_[l * 256 + hd * 64 + f];
    }
    was[l * 256 + k * 4 + hd] = s;
    wad[l * 256 + k * 4 + hd] = d;
}

// Combined C^T[l][f][kk] = sum_j W[l][k][hd*64+j] * lW[l][hd*64+j][f], kk=hd*64+k
__global__ void k_prep_cmb(const float* __restrict__ W, const float* __restrict__ lW,
                           u16* __restrict__ CT) {
    int i = blockIdx.x * 256 + threadIdx.x;
    if (i >= 2 * 64 * 256) return;
    int l = i >> 14, rem = i & 16383;
    int f = rem >> 8, kk = rem & 255;
    int hd = kk >> 6, k = kk & 63;
    float s = 0.f;
    for (int j = 0; j < 64; ++j)
        s += W[(size_t)l * 16384 + k * 256 + hd * 64 + j] *
             lW[(size_t)l * 16384 + (hd * 64 + j) * 64 + f];
    CT[(size_t)l * 16384 + f * 256 + kk] = f2bf(s);
}

// cb[l][f] = sum_j gb[l][j]*lW[l][j][f] + lb[l][f]
__global__ void k_prep_cb(const float* __restrict__ gb, const float* __restrict__ lW,
                          const float* __restrict__ lb, float* __restrict__ cb) {
    int i = blockIdx.x * 256 + threadIdx.x;
    if (i >= 2 * 64) return;
    int l = i >> 6, f = i & 63;
    float s = lb[l * 64 + f];
    for (int j = 0; j < 256; ++j)
        s += gb[l * 256 + j] * lW[(size_t)l * 16384 + j * 64 + f];
    cb[l * 64 + f] = s;
}

// f32 -> bf16 bulk convert (float4 -> ushort4)
__global__ void k_f2bf4(const float* __restrict__ src, u16* __restrict__ dst, int n4) {
    int i = blockIdx.x * 256 + threadIdx.x;
    if (i >= n4) return;
    float4 f = ((const float4*)src)[i];
    ((ushort4*)dst)[i] = f4tobf(f);
}

// gather bf16 rows into seq2 [row][128] at column offset held in dst base
__global__ void k_gather(const u16* __restrict__ x, const int* __restrict__ clf,
                         u16* __restrict__ dst) {
    int i = blockIdx.x * 256 + threadIdx.x;
    if (i >= NC * 16) return;
    int row = i >> 4, c4 = i & 15;
    int node = clf[row];
    ushort4 u = ((const ushort4*)x)[(size_t)node * 16 + c4];
    *(ushort4*)&dst[(size_t)row * 128 + c4 * 4] = u;
}

// ---------------- al/ar: x[N,64] dot was/wad[64][4] ----------------
__global__ __launch_bounds__(256) void k_alar_x(const u16* __restrict__ xb,
                                                const float* __restrict__ was,
                                                const float* __restrict__ wad,
                                                float* __restrict__ al,
                                                float* __restrict__ ar) {
    int lane = threadIdx.x & 63;
    int n = blockIdx.x * 16 + (threadIdx.x >> 6) * 4 + (lane >> 4);
    int q = lane & 15;
    ushort4 u = *(const ushort4*)&xb[(size_t)n * 64 + q * 4];
    float ps[4] = {0.f, 0.f, 0.f, 0.f};
    float pd[4] = {0.f, 0.f, 0.f, 0.f};
#pragma unroll
    for (int d = 0; d < 4; ++d) {
        u16 uv = (d == 0) ? u.x : (d == 1) ? u.y : (d == 2) ? u.z : u.w;
        float xv = bf2f(uv);
        int k = q * 4 + d;
        float4 w4 = *(const float4*)&was[k * 4];
        float4 d4 = *(const float4*)&wad[k * 4];
        ps[0] += xv * w4.x; ps[1] += xv * w4.y;
        ps[2] += xv * w4.z; ps[3] += xv * w4.w;
        pd[0] += xv * d4.x; pd[1] += xv * d4.y;
        pd[2] += xv * d4.z; pd[3] += xv * d4.w;
    }
#pragma unroll
    for (int o = 1; o < 16; o <<= 1) {
#pragma unroll
        for (int hd = 0; hd < 4; ++hd) {
            ps[hd] += __shfl_xor(ps[hd], o, 64);
            pd[hd] += __shfl_xor(pd[hd], o, 64);
        }
    }
    if (q == 0) {
        *(float4*)&al[n * 4] = make_float4(ps[0], ps[1], ps[2], ps[3]);
        *(float4*)&ar[n * 4] = make_float4(pd[0], pd[1], pd[2], pd[3]);
    }
}

// ---------------- attention aggregation over x, 2 edges/round, 4-deep pipeline ----
// (R17-verified best variant)
__global__ __launch_bounds__(256) void k_agg_x(const int* __restrict__ off,
                                               const int* __restrict__ csr,
                                               const float* __restrict__ al,
                                               const float* __restrict__ ar,
                                               const u16* __restrict__ xb,
                                               u16* __restrict__ xagg) {
    int lane = threadIdx.x & 63;
    int n = blockIdx.x * 4 + (threadIdx.x >> 6);
    int hh = lane & 3;
    int hf = lane >> 5;          // 0 = even edge of round, 1 = odd edge
    int kd = lane & 31;          // dim-pair index: dims 2kd, 2kd+1
    float ar_hh = ar[n * 4 + hh];
    int beg = off[n], end = off[n + 1];
    float den[4]  = {0.f, 0.f, 0.f, 0.f};
    float accL[4] = {0.f, 0.f, 0.f, 0.f};
    float accH[4] = {0.f, 0.f, 0.f, 0.f};

    for (int cbase = beg; cbase < end; cbase += 64) {
        int cnt = min(64, end - cbase);
        int sidx = csr[cbase + ((lane < cnt) ? lane : 0)];
        int nbat = (cnt + 15) >> 4;
        float pb[4];
#pragma unroll
        for (int b = 0; b < 4; ++b) {
            if (b < nbat) {
                int jj = b * 16 + (lane >> 2);
                int sj = __shfl(sidx, (jj < cnt) ? jj : 0, 64);
                pb[b] = expf(lrelu(al[sj * 4 + hh] + ar_hh));
            } else {
                pb[b] = 0.f;
            }
        }
        int R = (cnt + 1) >> 1;   // rounds of 2 edges

#define LDX(r, dstv)                                                         \
        {                                                                    \
            int jj_ = (r) * 2 + hf;                                          \
            int ss_ = __shfl(sidx, (jj_ < cnt) ? jj_ : 0, 64);               \
            dstv = *(const unsigned*)&xb[(size_t)ss_ * 64 + kd * 2];         \
        }
#define CONS(r, cv)                                                          \
        {                                                                    \
            int je_ = (r) * 2 + hf;                                          \
            int b_ = ((r) >> 3) & 3;                                         \
            float pbb_ = (b_ == 0) ? pb[0] : (b_ == 1) ? pb[1]               \
                        : (b_ == 2) ? pb[2] : pb[3];                         \
            float xlo_ = bf2f((u16)((cv) & 0xffffu));                        \
            float xhi_ = bf2f((u16)((cv) >> 16));                            \
            _Pragma("unroll")                                                \
            for (int hd_ = 0; hd_ < 4; ++hd_) {                              \
                float p_ = __shfl(pbb_, ((je_ & 15) << 2) | hd_, 64);        \
                p_ = (je_ < cnt) ? p_ : 0.f;                                 \
                accL[hd_] += p_ * xlo_;                                      \
                accH[hd_] += p_ * xhi_;                                      \
                den[hd_]  += p_;                                             \
            }                                                                \
        }

        unsigned c0, c1, c2, c3;
        LDX(0, c0); LDX(1, c1); LDX(2, c2); LDX(3, c3);
        for (int g = 0; g < R; g += 4) {
            unsigned n0 = 0, n1 = 0, n2 = 0, n3 = 0;
            if (g + 4 < R) {          // wave-uniform
                LDX(g + 4, n0); LDX(g + 5, n1); LDX(g + 6, n2); LDX(g + 7, n3);
            }
            CONS(g + 0, c0);
            if (g + 1 < R) CONS(g + 1, c1);
            if (g + 2 < R) CONS(g + 2, c2);
            if (g + 3 < R) CONS(g + 3, c3);
            c0 = n0; c1 = n1; c2 = n2; c3 = n3;
        }
#undef LDX
#undef CONS
    }
    // merge even/odd halves
#pragma unroll
    for (int hd = 0; hd < 4; ++hd) {
        accL[hd] += __shfl_xor(accL[hd], 32, 64);
        accH[hd] += __shfl_xor(accH[hd], 32, 64);
        den[hd]  += __shfl_xor(den[hd], 32, 64);
    }
    if (hf == 0) {
#pragma unroll
        for (int hd = 0; hd < 4; ++hd) {
            float inv = 1.f / (den[hd] + 1e-16f);
            unsigned w = (unsigned)f2bf(accL[hd] * inv) |
                         ((unsigned)f2bf(accH[hd] * inv) << 16);
            *(unsigned*)&xagg[(size_t)n * 256 + hd * 64 + kd * 2] = w;
        }
    }
}

// out[N,64](bf16) = relu(A[N,256](bf16) @ C[256,64] + cb)  -- MFMA 16x16x32
__global__ __launch_bounds__(256) void k_gemm_cmb(const u16* __restrict__ A,
                                                  const u16* __restrict__ CT,
                                                  const float* __restrict__ cb,
                                                  u16* __restrict__ out) {
    int lane = threadIdx.x & 63;
    int wid = threadIdx.x >> 6;
    int g = lane >> 4, c = lane & 15;
    int r0 = blockIdx.x * 64 + wid * 16;
    int arow = r0 + c; if (arow > NN - 1) arow = NN - 1;
    const u16* aptr = A + (size_t)arow * 256 + g * 8;
    const u16* bptr = CT + (size_t)c * 256 + g * 8;
    f32x4 acc[4];
#pragma unroll
    for (int t = 0; t < 4; ++t) acc[t] = (f32x4){0.f, 0.f, 0.f, 0.f};
#pragma unroll
    for (int ks = 0; ks < 8; ++ks) {
        bf16x8 af = *(const bf16x8*)(aptr + ks * 32);
#pragma unroll
        for (int t = 0; t < 4; ++t) {
            bf16x8 bfr = *(const bf16x8*)(bptr + t * 16 * 256 + ks * 32);
            acc[t] = __builtin_amdgcn_mfma_f32_16x16x32_bf16(af, bfr, acc[t], 0, 0, 0);
        }
    }
    int orow0 = r0 + g * 4;
#pragma unroll
    for (int t = 0; t < 4; ++t) {
        int col = t * 16 + c;
        float bv = cb[col];
#pragma unroll
        for (int j = 0; j < 4; ++j) {
            int row = orow0 + j;
            if (row < NN) out[(size_t)row * 64 + col] = f2bf(fmaxf(acc[t][j] + bv, 0.f));
        }
    }
}

// gx[M][256] = seq2[M][128](bf16) @ Wi1^T (Wi1b [256][128] bf16)  -- MFMA
__global__ __launch_bounds__(256) void k_gemm_gx(const u16* __restrict__ A,
                                                 const u16* __restrict__ BT,
                                                 float* __restrict__ gxout, int M) {
    int lane = threadIdx.x & 63;
    int wid = threadIdx.x >> 6;
    int g = lane >> 4, c = lane & 15;
    int r0 = blockIdx.x * 64 + wid * 16;
    int arow = r0 + c; if (arow > M - 1) arow = M - 1;
    const u16* aptr = A + (size_t)arow * 128 + g * 8;
    f32x4 acc[16];
#pragma unroll
    for (int t = 0; t < 16; ++t) acc[t] = (f32x4){0.f, 0.f, 0.f, 0.f};
#pragma unroll
    for (int ks = 0; ks < 4; ++ks) {
        bf16x8 af = *(const bf16x8*)(aptr + ks * 32);
#pragma unroll
        for (int t = 0; t < 16; ++t) {
            bf16x8 bfr = *(const bf16x8*)(BT + (size_t)(t * 16 + c) * 128 + ks * 32 + g * 8);
            acc[t] = __builtin_amdgcn_mfma_f32_16x16x32_bf16(af, bfr, acc[t], 0, 0, 0);
        }
    }
#pragma unroll
    for (int t = 0; t < 16; ++t) {
#pragma unroll
        for (int j = 0; j < 4; ++j) {
            int row = r0 + g * 4 + j;
            if (row < M) gxout[(size_t)row * 256 + t * 16 + c] = acc[t][j];
        }
    }
}

// ---------------- fused LSTM (recurrent part only) + FC, 8 rows/wave ---------
// LSTM1 x-contribution precomputed in gx; per step only K=64 (Wh1) + K=128 (LSTM2).
__global__ __launch_bounds__(256) void k_lstm_fc(const float* __restrict__ gx,
                                                 const float* __restrict__ WhT1,
                                                 const float* __restrict__ bb1,
                                                 const float* __restrict__ WiT2,
                                                 const float* __restrict__ WhT2,
                                                 const float* __restrict__ bb2,
                                                 const float* __restrict__ fw1,
                                                 const float* __restrict__ fb1,
                                                 const float* __restrict__ fw2,
                                                 const float* __restrict__ fb2,
                                                 float* __restrict__ out) {
    __shared__ float xs[4][8][128];
    int w = threadIdx.x >> 6, lane = threadIdx.x & 63;
    int row0 = blockIdx.x * 32 + w * 8;
    float h1[8], c1[8], h2[8], c2[8];
#pragma unroll
    for (int r = 0; r < 8; ++r) { h1[r] = 0.f; c1[r] = 0.f; h2[r] = 0.f; c2[r] = 0.f; }
    float bi1 = bb1[lane], bf1 = bb1[64 + lane], bg1 = bb1[128 + lane], bo1 = bb1[192 + lane];
    float bi2 = bb2[lane], bf2v = bb2[64 + lane], bg2 = bb2[128 + lane], bo2 = bb2[192 + lane];

    for (int st = 0; st < TT; ++st) {
        int tsn = TT - 1 - st;   // outs[::-1]
        // ---- LSTM1: gates = gx + Wh1 @ h1 + b
#pragma unroll
        for (int r = 0; r < 8; ++r) xs[w][r][lane] = h1[r];
        __syncthreads();
        {
            const float* gxp = gx + (size_t)tsn * NC * 256;
            float ai[8], af[8], ag[8], ao[8];
#pragma unroll
            for (int r = 0; r < 8; ++r) {
                const float* gr = gxp + (size_t)(row0 + r) * 256;
                ai[r] = bi1 + gr[lane];
                af[r] = bf1 + gr[64 + lane];
                ag[r] = bg1 + gr[128 + lane];
                ao[r] = bo1 + gr[192 + lane];
            }
            for (int k = 0; k < 64; ++k) {
                const float* wr = &WhT1[k * 256];
                float wi = wr[lane], wf = wr[64 + lane], wg = wr[128 + lane], wo = wr[192 + lane];
#pragma unroll
                for (int r = 0; r < 8; ++r) {
                    float hv = xs[w][r][k];
                    ai[r] += hv * wi; af[r] += hv * wf;
                    ag[r] += hv * wg; ao[r] += hv * wo;
                }
            }
#pragma unroll
            for (int r = 0; r < 8; ++r) {
                c1[r] = sigm(af[r]) * c1[r] + sigm(ai[r]) * tanhf(ag[r]);
                h1[r] = sigm(ao[r]) * tanhf(c1[r]);
            }
        }
        __syncthreads();
        // ---- LSTM2: x = h1 (64), h = h2
#pragma unroll
        for (int r = 0; r < 8; ++r) {
            xs[w][r][lane]      = h1[r];
            xs[w][r][64 + lane] = h2[r];
        }
        __syncthreads();
        {
            float ai[8], af[8], ag[8], ao[8];
#pragma unroll
            for (int r = 0; r < 8; ++r) { ai[r] = bi2; af[r] = bf2v; ag[r] = bg2; ao[r] = bo2; }
            for (int k = 0; k < 64; ++k) {
                const float* wr = &WiT2[k * 256];
                float wi = wr[lane], wf = wr[64 + lane], wg = wr[128 + lane], wo = wr[192 + lane];
#pragma unroll
                for (int r = 0; r < 8; ++r) {
                    float xv = xs[w][r][k];
                    ai[r] += xv * wi; af[r] += xv * wf;
                    ag[r] += xv * wg; ao[r] += xv * wo;
                }
            }
            for (int k = 0; k < 64; ++k) {
                const float* wr = &WhT2[k * 256];
                float wi = wr[lane], wf = wr[64 + lane], wg = wr[128 + lane], wo = wr[192 + lane];
#pragma unroll
                for (int r = 0; r < 8; ++r) {
                    float hv = xs[w][r][64 + k];
                    ai[r] += hv * wi; af[r] += hv * wf;
                    ag[r] += hv * wg; ao[r] += hv * wo;
                }
            }
#pragma unroll
            for (int r = 0; r < 8; ++r) {
                c2[r] = sigm(af[r]) * c2[r] + sigm(ai[r]) * tanhf(ag[r]);
                h2[r] = sigm(ao[r]) * tanhf(c2[r]);
            }
        }
        __syncthreads();
    }
    // ---- FC head: z = [h1 | h2]
#pragma unroll
    for (int r = 0; r < 8; ++r) {
        xs[w][r][lane]      = h1[r];
        xs[w][r][64 + lane] = h2[r];
    }
    __syncthreads();
    float acc[8];
#pragma unroll
    for (int r = 0; r < 8; ++r) acc[r] = fb1[lane];
    for (int k = 0; k < 128; ++k) {
        float wv = fw1[k * 64 + lane];
#pragma unroll
        for (int r = 0; r < 8; ++r) acc[r] += xs[w][r][k] * wv;
    }
    float w20 = fw2[lane * 2], w21 = fw2[lane * 2 + 1];
#pragma unroll
    for (int r = 0; r < 8; ++r) {
        float rr = fmaxf(acc[r], 0.f);
        float t0 = rr * w20;
        float t1 = rr * w21;
#pragma unroll
        for (int o = 32; o >= 1; o >>= 1) {
            t0 += __shfl_xor(t0, o, 64);
            t1 += __shfl_xor(t1, o, 64);
        }
        if (lane == 0) {
            out[(row0 + r) * 2]     = fmaxf(t0 + fb2[0], 0.f);
            out[(row0 + r) * 2 + 1] = fmaxf(t1 + fb2[1], 0.f);
        }
    }
}

extern "C" void kernel_launch(void* const* d_in, const int* in_sizes, int n_in,
                              void* d_out, int out_size, void* d_ws, size_t ws_size,
                              hipStream_t stream) {
    const float* emb  = (const float*)d_in[0];
    const float* g1W  = (const float*)d_in[1];
    const float* g1as = (const float*)d_in[2];
    const float* g1ad = (const float*)d_in[3];
    const float* g1b  = (const float*)d_in[4];
    const float* l1W  = (const float*)d_in[5];
    const float* l1b  = (const float*)d_in[6];
    const float* g2W  = (const float*)d_in[7];
    const float* g2as = (const float*)d_in[8];
    const float* g2ad = (const float*)d_in[9];
    const float* g2b  = (const float*)d_in[10];
    const float* l2W  = (const float*)d_in[11];
    const float* l2b  = (const float*)d_in[12];
    const float* Wi1  = (const float*)d_in[13];
    const float* Wh1  = (const float*)d_in[14];
    const float* b1   = (const float*)d_in[15];
    const float* Wi2  = (const float*)d_in[16];
    const float* Wh2  = (const float*)d_in[17];
    const float* b2   = (const float*)d_in[18];
    const float* fc1W = (const float*)d_in[19];
    const float* fc1b = (const float*)d_in[20];
    const float* fc2W = (const float*)d_in[21];
    const float* fc2b = (const float*)d_in[22];
    const int* edges = (const int*)d_in[23];
    const int* clf   = (const int*)d_in[27];

    char* ws = (char*)d_ws;
    size_t woff = 0;
    auto alloc = [&](size_t bytes) -> void* {
        void* p = ws + woff;
        woff += (bytes + 255) & ~(size_t)255;
        return p;
    };
    int* csr_off  = (int*)alloc((size_t)TT * (NN + 1) * 4);
    int* csr_fil  = (int*)alloc((size_t)TT * NN * 4);
    int* csr_src  = (int*)alloc((size_t)TT * ET * 4);
    int* scan_sum = (int*)alloc((size_t)TT * NCH * 4);
    int* scan_bas = (int*)alloc((size_t)TT * NCH * 4);
    u16* embb     = (u16*)alloc((size_t)TT * NN * 64 * 2);
    u16* xbuf     = (u16*)alloc((size_t)NN * 64 * 2);
    u16* xaggb    = (u16*)alloc((size_t)NN * 256 * 2);
    float* albuf  = (float*)alloc((size_t)NN * 4 * 4);
    float* arbuf  = (float*)alloc((size_t)NN * 4 * 4);
    u16* seq2     = (u16*)alloc((size_t)TT * NC * 128 * 2);   // [t][row][e1|e2] bf16
    float* gxb    = (float*)alloc((size_t)TT * NC * 256 * 4); // LSTM1 x-gates
    float* WhT1   = (float*)alloc(64 * 256 * 4);
    float* WiT2   = (float*)alloc(64 * 256 * 4);
    float* WhT2   = (float*)alloc(64 * 256 * 4);
    u16* wi1b     = (u16*)alloc((size_t)256 * 128 * 2);       // Wi1 bf16 [256][128]
    u16* CT1      = (u16*)alloc((size_t)2 * 64 * 256 * 2);    // [L][64][256] bf16
    u16* CT2      = (u16*)alloc((size_t)2 * 64 * 256 * 2);
    float* cb1    = (float*)alloc((size_t)2 * 64 * 4);
    float* cb2    = (float*)alloc((size_t)2 * 64 * 4);
    float* wasb1  = (float*)alloc((size_t)2 * 64 * 4 * 4);    // [L][64][4]
    float* wadb1  = (float*)alloc((size_t)2 * 64 * 4 * 4);
    float* wasb2  = (float*)alloc((size_t)2 * 64 * 4 * 4);
    float* wadb2  = (float*)alloc((size_t)2 * 64 * 4 * 4);

    // CSR build (per snapshot, includes self-loops)
    k_fill1<<<(TT * NN + 255) / 256, 256, 0, stream>>>(csr_fil, TT * NN);
    k_count<<<(TT * EE + 255) / 256, 256, 0, stream>>>(edges, csr_fil);
    k_scan1<<<TT * NCH, 256, 0, stream>>>(csr_fil, scan_sum);
    k_scan2<<<TT, 256, 0, stream>>>(scan_sum, scan_bas, csr_off);
    k_scan3<<<TT * NCH, 256, 0, stream>>>(csr_fil, scan_bas, csr_off);
    k_csrfill<<<(TT * ET + 255) / 256, 256, 0, stream>>>(edges, csr_fil, csr_src);

    // weight preps
    k_transpose<<<(256 * 64 + 255) / 256, 256, 0, stream>>>(Wh1, WhT1, 256, 64);
    k_transpose<<<(256 * 64 + 255) / 256, 256, 0, stream>>>(Wi2, WiT2, 256, 64);
    k_transpose<<<(256 * 64 + 255) / 256, 256, 0, stream>>>(Wh2, WhT2, 256, 64);
    k_prep_wi1<<<(256 * 128 + 255) / 256, 256, 0, stream>>>(Wi1, wi1b);
    k_prep_was<<<2, 256, 0, stream>>>(g1W, g1as, g1ad, wasb1, wadb1);
    k_prep_was<<<2, 256, 0, stream>>>(g2W, g2as, g2ad, wasb2, wadb2);
    k_prep_cmb<<<(2 * 64 * 256 + 255) / 256, 256, 0, stream>>>(g1W, l1W, CT1);
    k_prep_cmb<<<(2 * 64 * 256 + 255) / 256, 256, 0, stream>>>(g2W, l2W, CT2);
    k_prep_cb<<<1, 256, 0, stream>>>(g1b, l1W, l1b, cb1);
    k_prep_cb<<<1, 256, 0, stream>>>(g2b, l2W, l2b, cb2);
    // emb -> bf16
    k_f2bf4<<<(TT * NN * 16 + 255) / 256, 256, 0, stream>>>(emb, embb, TT * NN * 16);

    for (int s = 0; s < 2; ++s) {
        const float* was = s ? wasb2 : wasb1;
        const float* wad = s ? wadb2 : wadb1;
        const u16* CT    = s ? CT2 : CT1;
        const float* cbp = s ? cb2 : cb1;
        for (int t = 0; t < TT; ++t) {
            for (int l = 0; l < 2; ++l) {
                const u16* xin = (l == 0) ? (embb + (size_t)t * NN * 64) : xbuf;
                k_alar_x<<<NN / 16, 256, 0, stream>>>(
                    xin, was + l * 256, wad + l * 256, albuf, arbuf);
                k_agg_x<<<NN / 4, 256, 0, stream>>>(
                    csr_off + (size_t)t * (NN + 1), csr_src + (size_t)t * ET,
                    albuf, arbuf, xin, xaggb);
                k_gemm_cmb<<<(NN + 63) / 64, 256, 0, stream>>>(
                    xaggb, CT + (size_t)l * 16384, cbp + l * 64, xbuf);
            }
            // seq2[t][row][s*64 .. s*64+63] = xbuf[clf[row]] (bf16)
            k_gather<<<(NC * 16 + 255) / 256, 256, 0, stream>>>(
                xbuf, clf, seq2 + (size_t)t * NC * 128 + s * 64);
        }
    }

    // LSTM1 x-gates for all steps: gx = seq2 @ Wi1^T  (M = TT*NC)
    k_gemm_gx<<<(TT * NC + 63) / 64, 256, 0, stream>>>(seq2, wi1b, gxb, TT * NC);

    // fused recurrent LSTM + FC, 8 rows/wave
    k_lstm_fc<<<NC / 32, 256, 0, stream>>>(
        gxb, WhT1, b1, WiT2, WhT2, b2,
        fc1W, fc1b, fc2W, fc2b, (float*)d_out);
}

// Round 25
// 1756.860 us; speedup vs baseline: 1.0509x; 1.0190x over previous
//
#include <hip/hip_runtime.h>

#define NN 50000
#define TT 5
#define EE 500000
#define NC 8192
#define ET (EE + NN)
#define NCH 196   // ceil(NN/256)

typedef unsigned short u16;
typedef __attribute__((ext_vector_type(8))) short bf16x8;
typedef __attribute__((ext_vector_type(4))) float f32x4;

__device__ __forceinline__ float lrelu(float x) { return x >= 0.f ? x : 0.2f * x; }
__device__ __forceinline__ float sigm(float x) { return 1.f / (1.f + expf(-x)); }
__device__ __forceinline__ float bf2f(u16 u) {
    union { unsigned int i; float f; } v; v.i = ((unsigned int)u) << 16; return v.f;
}
__device__ __forceinline__ u16 f2bf(float f) {
    unsigned int x = __float_as_uint(f);
    return (u16)((x + 0x7fffu + ((x >> 16) & 1u)) >> 16);
}
__device__ __forceinline__ ushort4 f4tobf(float4 v) {
    ushort4 u; u.x = f2bf(v.x); u.y = f2bf(v.y); u.z = f2bf(v.z); u.w = f2bf(v.w);
    return u;
}
__device__ __forceinline__ float4 bf4tof(ushort4 u) {
    return make_float4(bf2f(u.x), bf2f(u.y), bf2f(u.z), bf2f(u.w));
}

// ---------------- CSR build ----------------
__global__ void k_fill1(int* p, int n) {
    int i = blockIdx.x * 256 + threadIdx.x;
    if (i < n) p[i] = 1;
}

__global__ void k_count(const int* __restrict__ edges, int* __restrict__ cnt) {
    int i = blockIdx.x * 256 + threadIdx.x;
    if (i >= TT * EE) return;
    int t = i / EE, e = i % EE;
    int dst = edges[(size_t)t * 2 * EE + EE + e];
    atomicAdd(&cnt[t * NN + dst], 1);
}

__global__ __launch_bounds__(256) void k_scan1(const int* __restrict__ cnt,
                                               int* __restrict__ sums) {
    int t = blockIdx.x / NCH, ch = blockIdx.x % NCH;
    int i = ch * 256 + threadIdx.x;
    int v = (i < NN) ? cnt[t * NN + i] : 0;
    __shared__ int s[256];
    s[threadIdx.x] = v;
    __syncthreads();
    for (int o = 128; o > 0; o >>= 1) {
        if (threadIdx.x < o) s[threadIdx.x] += s[threadIdx.x + o];
        __syncthreads();
    }
    if (threadIdx.x == 0) sums[t * NCH + ch] = s[0];
}

__global__ __launch_bounds__(256) void k_scan2(const int* __restrict__ sums,
                                               int* __restrict__ bases,
                                               int* __restrict__ off) {
    int t = blockIdx.x;
    __shared__ int s[256];
    int v = (threadIdx.x < NCH) ? sums[t * NCH + threadIdx.x] : 0;
    s[threadIdx.x] = v;
    __syncthreads();
    for (int o = 1; o < 256; o <<= 1) {
        int tv = (threadIdx.x >= o) ? s[threadIdx.x - o] : 0;
        __syncthreads();
        s[threadIdx.x] += tv;
        __syncthreads();
    }
    if (threadIdx.x < NCH) bases[t * NCH + threadIdx.x] = s[threadIdx.x] - v;
    if (threadIdx.x == 255) off[t * (NN + 1) + NN] = s[255];
}

__global__ __launch_bounds__(256) void k_scan3(int* __restrict__ cnt,
                                               const int* __restrict__ bases,
                                               int* __restrict__ off) {
    int t = blockIdx.x / NCH, ch = blockIdx.x % NCH;
    int i = ch * 256 + threadIdx.x;
    int v = (i < NN) ? cnt[t * NN + i] : 0;
    __shared__ int s[256];
    s[threadIdx.x] = v;
    __syncthreads();
    for (int o = 1; o < 256; o <<= 1) {
        int tv = (threadIdx.x >= o) ? s[threadIdx.x - o] : 0;
        __syncthreads();
        s[threadIdx.x] += tv;
        __syncthreads();
    }
    if (i < NN) {
        int excl = bases[t * NCH + ch] + s[threadIdx.x] - v;
        off[t * (NN + 1) + i] = excl;
        cnt[t * NN + i] = excl;  // becomes fill pointer
    }
}

__global__ void k_csrfill(const int* __restrict__ edges, int* __restrict__ fil,
                          int* __restrict__ csr) {
    int i = blockIdx.x * 256 + threadIdx.x;
    if (i >= TT * ET) return;
    int t = i / ET, r = i % ET;
    int src, dst;
    if (r < EE) {
        src = edges[(size_t)t * 2 * EE + r];
        dst = edges[(size_t)t * 2 * EE + EE + r];
    } else {
        src = dst = r - EE;
    }
    int pos = atomicAdd(&fil[t * NN + dst], 1);
    csr[(size_t)t * ET + pos] = src;
}

// ---------------- prep ----------------
__global__ void k_transpose(const float* __restrict__ src, float* __restrict__ dst,
                            int R, int C) {
    int i = blockIdx.x * 256 + threadIdx.x;
    if (i >= R * C) return;
    int r = i / C, c = i % C;
    dst[c * R + r] = src[i];
}

// Wi1 [256][128] f32 -> bf16 (already gate-major, k-contiguous = MFMA B format)
__global__ void k_prep_wi1(const float* __restrict__ W, u16* __restrict__ Wb) {
    int i = blockIdx.x * 256 + threadIdx.x;
    if (i >= 256 * 128) return;
    Wb[i] = f2bf(W[i]);
}

// was/wad[l][k][hd] = sum_f W[l][k][hd*64+f] * a[l][hd][f]   (f32-exact)
__global__ void k_prep_was(const float* __restrict__ W,
                           const float* __restrict__ as_,
                           const float* __restrict__ ad_,
                           float* __restrict__ was, float* __restrict__ wad) {
    int id = blockIdx.x * 256 + threadIdx.x;
    if (id >= 2 * 64 * 4) return;
    int l = id >> 8, rem = id & 255;
    int k = rem >> 2, hd = rem & 3;
    float s = 0.f, d = 0.f;
    for (int f = 0; f < 64; ++f) {
        float w = W[(size_t)l * 16384 + k * 256 + hd * 64 + f];
        s += w * as_[l * 256 + hd * 64 + f];
        d += w * ad_[l * 256 + hd * 64 + f];
    }
    was[l * 256 + k * 4 + hd] = s;
    wad[l * 256 + k * 4 + hd] = d;
}

// Combined C^T[l][f][kk] = sum_j W[l][k][hd*64+j] * lW[l][hd*64+j][f], kk=hd*64+k
__global__ void k_prep_cmb(const float* __restrict__ W, const float* __restrict__ lW,
                           u16* __restrict__ CT) {
    int i = blockIdx.x * 256 + threadIdx.x;
    if (i >= 2 * 64 * 256) return;
    int l = i >> 14, rem = i & 16383;
    int f = rem >> 8, kk = rem & 255;
    int hd = kk >> 6, k = kk & 63;
    float s = 0.f;
    for (int j = 0; j < 64; ++j)
        s += W[(size_t)l * 16384 + k * 256 + hd * 64 + j] *
             lW[(size_t)l * 16384 + (hd * 64 + j) * 64 + f];
    CT[(size_t)l * 16384 + f * 256 + kk] = f2bf(s);
}

// cb[l][f] = sum_j gb[l][j]*lW[l][j][f] + lb[l][f]
__global__ void k_prep_cb(const float* __restrict__ gb, const float* __restrict__ lW,
                          const float* __restrict__ lb, float* __restrict__ cb) {
    int i = blockIdx.x * 256 + threadIdx.x;
    if (i >= 2 * 64) return;
    int l = i >> 6, f = i & 63;
    float s = lb[l * 64 + f];
    for (int j = 0; j < 256; ++j)
        s += gb[l * 256 + j] * lW[(size_t)l * 16384 + j * 64 + f];
    cb[l * 64 + f] = s;
}

// f32 -> bf16 bulk convert (float4 -> ushort4)
__global__ void k_f2bf4(const float* __restrict__ src, u16* __restrict__ dst, int n4) {
    int i = blockIdx.x * 256 + threadIdx.x;
    if (i >= n4) return;
    float4 f = ((const float4*)src)[i];
    ((ushort4*)dst)[i] = f4tobf(f);
}

// gather bf16 rows into seq2 [row][128] at column offset held in dst base
__global__ void k_gather(const u16* __restrict__ x, const int* __restrict__ clf,
                         u16* __restrict__ dst) {
    int i = blockIdx.x * 256 + threadIdx.x;
    if (i >= NC * 16) return;
    int row = i >> 4, c4 = i & 15;
    int node = clf[row];
    ushort4 u = ((const ushort4*)x)[(size_t)node * 16 + c4];
    *(ushort4*)&dst[(size_t)row * 128 + c4 * 4] = u;
}

// ---------------- al/ar: x[N,64] dot was/wad[64][4] ----------------
__global__ __launch_bounds__(256) void k_alar_x(const u16* __restrict__ xb,
                                                const float* __restrict__ was,
                                                const float* __restrict__ wad,
                                                float* __restrict__ al,
                                                float* __restrict__ ar) {
    int lane = threadIdx.x & 63;
    int n = blockIdx.x * 16 + (threadIdx.x >> 6) * 4 + (lane >> 4);
    int q = lane & 15;
    ushort4 u = *(const ushort4*)&xb[(size_t)n * 64 + q * 4];
    float ps[4] = {0.f, 0.f, 0.f, 0.f};
    float pd[4] = {0.f, 0.f, 0.f, 0.f};
#pragma unroll
    for (int d = 0; d < 4; ++d) {
        u16 uv = (d == 0) ? u.x : (d == 1) ? u.y : (d == 2) ? u.z : u.w;
        float xv = bf2f(uv);
        int k = q * 4 + d;
        float4 w4 = *(const float4*)&was[k * 4];
        float4 d4 = *(const float4*)&wad[k * 4];
        ps[0] += xv * w4.x; ps[1] += xv * w4.y;
        ps[2] += xv * w4.z; ps[3] += xv * w4.w;
        pd[0] += xv * d4.x; pd[1] += xv * d4.y;
        pd[2] += xv * d4.z; pd[3] += xv * d4.w;
    }
#pragma unroll
    for (int o = 1; o < 16; o <<= 1) {
#pragma unroll
        for (int hd = 0; hd < 4; ++hd) {
            ps[hd] += __shfl_xor(ps[hd], o, 64);
            pd[hd] += __shfl_xor(pd[hd], o, 64);
        }
    }
    if (q == 0) {
        *(float4*)&al[n * 4] = make_float4(ps[0], ps[1], ps[2], ps[3]);
        *(float4*)&ar[n * 4] = make_float4(pd[0], pd[1], pd[2], pd[3]);
    }
}

// ---------------- attention aggregation over x, 2 edges/round, 4-deep pipeline ----
// (R17-verified best variant)
__global__ __launch_bounds__(256) void k_agg_x(const int* __restrict__ off,
                                               const int* __restrict__ csr,
                                               const float* __restrict__ al,
                                               const float* __restrict__ ar,
                                               const u16* __restrict__ xb,
                                               u16* __restrict__ xagg) {
    int lane = threadIdx.x & 63;
    int n = blockIdx.x * 4 + (threadIdx.x >> 6);
    int hh = lane & 3;
    int hf = lane >> 5;          // 0 = even edge of round, 1 = odd edge
    int kd = lane & 31;          // dim-pair index: dims 2kd, 2kd+1
    float ar_hh = ar[n * 4 + hh];
    int beg = off[n], end = off[n + 1];
    float den[4]  = {0.f, 0.f, 0.f, 0.f};
    float accL[4] = {0.f, 0.f, 0.f, 0.f};
    float accH[4] = {0.f, 0.f, 0.f, 0.f};

    for (int cbase = beg; cbase < end; cbase += 64) {
        int cnt = min(64, end - cbase);
        int sidx = csr[cbase + ((lane < cnt) ? lane : 0)];
        int nbat = (cnt + 15) >> 4;
        float pb[4];
#pragma unroll
        for (int b = 0; b < 4; ++b) {
            if (b < nbat) {
                int jj = b * 16 + (lane >> 2);
                int sj = __shfl(sidx, (jj < cnt) ? jj : 0, 64);
                pb[b] = expf(lrelu(al[sj * 4 + hh] + ar_hh));
            } else {
                pb[b] = 0.f;
            }
        }
        int R = (cnt + 1) >> 1;   // rounds of 2 edges

#define LDX(r, dstv)                                                         \
        {                                                                    \
            int jj_ = (r) * 2 + hf;                                          \
            int ss_ = __shfl(sidx, (jj_ < cnt) ? jj_ : 0, 64);               \
            dstv = *(const unsigned*)&xb[(size_t)ss_ * 64 + kd * 2];         \
        }
#define CONS(r, cv)                                                          \
        {                                                                    \
            int je_ = (r) * 2 + hf;                                          \
            int b_ = ((r) >> 3) & 3;                                         \
            float pbb_ = (b_ == 0) ? pb[0] : (b_ == 1) ? pb[1]               \
                        : (b_ == 2) ? pb[2] : pb[3];                         \
            float xlo_ = bf2f((u16)((cv) & 0xffffu));                        \
            float xhi_ = bf2f((u16)((cv) >> 16));                            \
            _Pragma("unroll")                                                \
            for (int hd_ = 0; hd_ < 4; ++hd_) {                              \
                float p_ = __shfl(pbb_, ((je_ & 15) << 2) | hd_, 64);        \
                p_ = (je_ < cnt) ? p_ : 0.f;                                 \
                accL[hd_] += p_ * xlo_;                                      \
                accH[hd_] += p_ * xhi_;                                      \
                den[hd_]  += p_;                                             \
            }                                                                \
        }

        unsigned c0, c1, c2, c3;
        LDX(0, c0); LDX(1, c1); LDX(2, c2); LDX(3, c3);
        for (int g = 0; g < R; g += 4) {
            unsigned n0 = 0, n1 = 0, n2 = 0, n3 = 0;
            if (g + 4 < R) {          // wave-uniform
                LDX(g + 4, n0); LDX(g + 5, n1); LDX(g + 6, n2); LDX(g + 7, n3);
            }
            CONS(g + 0, c0);
            if (g + 1 < R) CONS(g + 1, c1);
            if (g + 2 < R) CONS(g + 2, c2);
            if (g + 3 < R) CONS(g + 3, c3);
            c0 = n0; c1 = n1; c2 = n2; c3 = n3;
        }
#undef LDX
#undef CONS
    }
    // merge even/odd halves
#pragma unroll
    for (int hd = 0; hd < 4; ++hd) {
        accL[hd] += __shfl_xor(accL[hd], 32, 64);
        accH[hd] += __shfl_xor(accH[hd], 32, 64);
        den[hd]  += __shfl_xor(den[hd], 32, 64);
    }
    if (hf == 0) {
#pragma unroll
        for (int hd = 0; hd < 4; ++hd) {
            float inv = 1.f / (den[hd] + 1e-16f);
            unsigned w = (unsigned)f2bf(accL[hd] * inv) |
                         ((unsigned)f2bf(accH[hd] * inv) << 16);
            *(unsigned*)&xagg[(size_t)n * 256 + hd * 64 + kd * 2] = w;
        }
    }
}

// out[N,64](bf16) = relu(A[N,256](bf16) @ C[256,64] + cb)  -- MFMA 16x16x32
__global__ __launch_bounds__(256) void k_gemm_cmb(const u16* __restrict__ A,
                                                  const u16* __restrict__ CT,
                                                  const float* __restrict__ cb,
                                                  u16* __restrict__ out) {
    int lane = threadIdx.x & 63;
    int wid = threadIdx.x >> 6;
    int g = lane >> 4, c = lane & 15;
    int r0 = blockIdx.x * 64 + wid * 16;
    int arow = r0 + c; if (arow > NN - 1) arow = NN - 1;
    const u16* aptr = A + (size_t)arow * 256 + g * 8;
    const u16* bptr = CT + (size_t)c * 256 + g * 8;
    f32x4 acc[4];
#pragma unroll
    for (int t = 0; t < 4; ++t) acc[t] = (f32x4){0.f, 0.f, 0.f, 0.f};
#pragma unroll
    for (int ks = 0; ks < 8; ++ks) {
        bf16x8 af = *(const bf16x8*)(aptr + ks * 32);
#pragma unroll
        for (int t = 0; t < 4; ++t) {
            bf16x8 bfr = *(const bf16x8*)(bptr + t * 16 * 256 + ks * 32);
            acc[t] = __builtin_amdgcn_mfma_f32_16x16x32_bf16(af, bfr, acc[t], 0, 0, 0);
        }
    }
    int orow0 = r0 + g * 4;
#pragma unroll
    for (int t = 0; t < 4; ++t) {
        int col = t * 16 + c;
        float bv = cb[col];
#pragma unroll
        for (int j = 0; j < 4; ++j) {
            int row = orow0 + j;
            if (row < NN) out[(size_t)row * 64 + col] = f2bf(fmaxf(acc[t][j] + bv, 0.f));
        }
    }
}

// gx[M][256] = seq2[M][128](bf16) @ Wi1^T (Wi1b [256][128] bf16)  -- MFMA
__global__ __launch_bounds__(256) void k_gemm_gx(const u16* __restrict__ A,
                                                 const u16* __restrict__ BT,
                                                 float* __restrict__ gxout, int M) {
    int lane = threadIdx.x & 63;
    int wid = threadIdx.x >> 6;
    int g = lane >> 4, c = lane & 15;
    int r0 = blockIdx.x * 64 + wid * 16;
    int arow = r0 + c; if (arow > M - 1) arow = M - 1;
    const u16* aptr = A + (size_t)arow * 128 + g * 8;
    f32x4 acc[16];
#pragma unroll
    for (int t = 0; t < 16; ++t) acc[t] = (f32x4){0.f, 0.f, 0.f, 0.f};
#pragma unroll
    for (int ks = 0; ks < 4; ++ks) {
        bf16x8 af = *(const bf16x8*)(aptr + ks * 32);
#pragma unroll
        for (int t = 0; t < 16; ++t) {
            bf16x8 bfr = *(const bf16x8*)(BT + (size_t)(t * 16 + c) * 128 + ks * 32 + g * 8);
            acc[t] = __builtin_amdgcn_mfma_f32_16x16x32_bf16(af, bfr, acc[t], 0, 0, 0);
        }
    }
#pragma unroll
    for (int t = 0; t < 16; ++t) {
#pragma unroll
        for (int j = 0; j < 4; ++j) {
            int row = r0 + g * 4 + j;
            if (row < M) gxout[(size_t)row * 256 + t * 16 + c] = acc[t][j];
        }
    }
}

// ---------------- fused LSTM (recurrent part only) + FC, 4 rows/wave ---------
// NR=4 doubles wave count (2 waves/SIMD) to hide gx/weight L2 latency.
__global__ __launch_bounds__(256) void k_lstm_fc(const float* __restrict__ gx,
                                                 const float* __restrict__ WhT1,
                                                 const float* __restrict__ bb1,
                                                 const float* __restrict__ WiT2,
                                                 const float* __restrict__ WhT2,
                                                 const float* __restrict__ bb2,
                                                 const float* __restrict__ fw1,
                                                 const float* __restrict__ fb1,
                                                 const float* __restrict__ fw2,
                                                 const float* __restrict__ fb2,
                                                 float* __restrict__ out) {
    __shared__ float xs[4][4][128];
    int w = threadIdx.x >> 6, lane = threadIdx.x & 63;
    int row0 = blockIdx.x * 16 + w * 4;
    float h1[4], c1[4], h2[4], c2[4];
#pragma unroll
    for (int r = 0; r < 4; ++r) { h1[r] = 0.f; c1[r] = 0.f; h2[r] = 0.f; c2[r] = 0.f; }
    float bi1 = bb1[lane], bf1 = bb1[64 + lane], bg1 = bb1[128 + lane], bo1 = bb1[192 + lane];
    float bi2 = bb2[lane], bf2v = bb2[64 + lane], bg2 = bb2[128 + lane], bo2 = bb2[192 + lane];

    for (int st = 0; st < TT; ++st) {
        int tsn = TT - 1 - st;   // outs[::-1]
        // ---- LSTM1: gates = gx + Wh1 @ h1 + b
#pragma unroll
        for (int r = 0; r < 4; ++r) xs[w][r][lane] = h1[r];
        __syncthreads();
        {
            const float* gxp = gx + (size_t)tsn * NC * 256;
            float ai[4], af[4], ag[4], ao[4];
#pragma unroll
            for (int r = 0; r < 4; ++r) {
                const float* gr = gxp + (size_t)(row0 + r) * 256;
                ai[r] = bi1 + gr[lane];
                af[r] = bf1 + gr[64 + lane];
                ag[r] = bg1 + gr[128 + lane];
                ao[r] = bo1 + gr[192 + lane];
            }
            for (int k = 0; k < 64; ++k) {
                const float* wr = &WhT1[k * 256];
                float wi = wr[lane], wf = wr[64 + lane], wg = wr[128 + lane], wo = wr[192 + lane];
#pragma unroll
                for (int r = 0; r < 4; ++r) {
                    float hv = xs[w][r][k];
                    ai[r] += hv * wi; af[r] += hv * wf;
                    ag[r] += hv * wg; ao[r] += hv * wo;
                }
            }
#pragma unroll
            for (int r = 0; r < 4; ++r) {
                c1[r] = sigm(af[r]) * c1[r] + sigm(ai[r]) * tanhf(ag[r]);
                h1[r] = sigm(ao[r]) * tanhf(c1[r]);
            }
        }
        __syncthreads();
        // ---- LSTM2: x = h1 (64), h = h2
#pragma unroll
        for (int r = 0; r < 4; ++r) {
            xs[w][r][lane]      = h1[r];
            xs[w][r][64 + lane] = h2[r];
        }
        __syncthreads();
        {
            float ai[4], af[4], ag[4], ao[4];
#pragma unroll
            for (int r = 0; r < 4; ++r) { ai[r] = bi2; af[r] = bf2v; ag[r] = bg2; ao[r] = bo2; }
            for (int k = 0; k < 64; ++k) {
                const float* wr = &WiT2[k * 256];
                float wi = wr[lane], wf = wr[64 + lane], wg = wr[128 + lane], wo = wr[192 + lane];
#pragma unroll
                for (int r = 0; r < 4; ++r) {
                    float xv = xs[w][r][k];
                    ai[r] += xv * wi; af[r] += xv * wf;
                    ag[r] += xv * wg; ao[r] += xv * wo;
                }
            }
            for (int k = 0; k < 64; ++k) {
                const float* wr = &WhT2[k * 256];
                float wi = wr[lane], wf = wr[64 + lane], wg = wr[128 + lane], wo = wr[192 + lane];
#pragma unroll
                for (int r = 0; r < 4; ++r) {
                    float hv = xs[w][r][64 + k];
                    ai[r] += hv * wi; af[r] += hv * wf;
                    ag[r] += hv * wg; ao[r] += hv * wo;
                }
            }
#pragma unroll
            for (int r = 0; r < 4; ++r) {
                c2[r] = sigm(af[r]) * c2[r] + sigm(ai[r]) * tanhf(ag[r]);
                h2[r] = sigm(ao[r]) * tanhf(c2[r]);
            }
        }
        __syncthreads();
    }
    // ---- FC head: z = [h1 | h2]
#pragma unroll
    for (int r = 0; r < 4; ++r) {
        xs[w][r][lane]      = h1[r];
        xs[w][r][64 + lane] = h2[r];
    }
    __syncthreads();
    float acc[4];
#pragma unroll
    for (int r = 0; r < 4; ++r) acc[r] = fb1[lane];
    for (int k = 0; k < 128; ++k) {
        float wv = fw1[k * 64 + lane];
#pragma unroll
        for (int r = 0; r < 4; ++r) acc[r] += xs[w][r][k] * wv;
    }
    float w20 = fw2[lane * 2], w21 = fw2[lane * 2 + 1];
#pragma unroll
    for (int r = 0; r < 4; ++r) {
        float rr = fmaxf(acc[r], 0.f);
        float t0 = rr * w20;
        float t1 = rr * w21;
#pragma unroll
        for (int o = 32; o >= 1; o >>= 1) {
            t0 += __shfl_xor(t0, o, 64);
            t1 += __shfl_xor(t1, o, 64);
        }
        if (lane == 0) {
            out[(row0 + r) * 2]     = fmaxf(t0 + fb2[0], 0.f);
            out[(row0 + r) * 2 + 1] = fmaxf(t1 + fb2[1], 0.f);
        }
    }
}

extern "C" void kernel_launch(void* const* d_in, const int* in_sizes, int n_in,
                              void* d_out, int out_size, void* d_ws, size_t ws_size,
                              hipStream_t stream) {
    const float* emb  = (const float*)d_in[0];
    const float* g1W  = (const float*)d_in[1];
    const float* g1as = (const float*)d_in[2];
    const float* g1ad = (const float*)d_in[3];
    const float* g1b  = (const float*)d_in[4];
    const float* l1W  = (const float*)d_in[5];
    const float* l1b  = (const float*)d_in[6];
    const float* g2W  = (const float*)d_in[7];
    const float* g2as = (const float*)d_in[8];
    const float* g2ad = (const float*)d_in[9];
    const float* g2b  = (const float*)d_in[10];
    const float* l2W  = (const float*)d_in[11];
    const float* l2b  = (const float*)d_in[12];
    const float* Wi1  = (const float*)d_in[13];
    const float* Wh1  = (const float*)d_in[14];
    const float* b1   = (const float*)d_in[15];
    const float* Wi2  = (const float*)d_in[16];
    const float* Wh2  = (const float*)d_in[17];
    const float* b2   = (const float*)d_in[18];
    const float* fc1W = (const float*)d_in[19];
    const float* fc1b = (const float*)d_in[20];
    const float* fc2W = (const float*)d_in[21];
    const float* fc2b = (const float*)d_in[22];
    const int* edges = (const int*)d_in[23];
    const int* clf   = (const int*)d_in[27];

    char* ws = (char*)d_ws;
    size_t woff = 0;
    auto alloc = [&](size_t bytes) -> void* {
        void* p = ws + woff;
        woff += (bytes + 255) & ~(size_t)255;
        return p;
    };
    int* csr_off  = (int*)alloc((size_t)TT * (NN + 1) * 4);
    int* csr_fil  = (int*)alloc((size_t)TT * NN * 4);
    int* csr_src  = (int*)alloc((size_t)TT * ET * 4);
    int* scan_sum = (int*)alloc((size_t)TT * NCH * 4);
    int* scan_bas = (int*)alloc((size_t)TT * NCH * 4);
    u16* embb     = (u16*)alloc((size_t)TT * NN * 64 * 2);
    u16* xbuf     = (u16*)alloc((size_t)NN * 64 * 2);
    u16* xaggb    = (u16*)alloc((size_t)NN * 256 * 2);
    float* albuf  = (float*)alloc((size_t)NN * 4 * 4);
    float* arbuf  = (float*)alloc((size_t)NN * 4 * 4);
    u16* seq2     = (u16*)alloc((size_t)TT * NC * 128 * 2);   // [t][row][e1|e2] bf16
    float* gxb    = (float*)alloc((size_t)TT * NC * 256 * 4); // LSTM1 x-gates
    float* WhT1   = (float*)alloc(64 * 256 * 4);
    float* WiT2   = (float*)alloc(64 * 256 * 4);
    float* WhT2   = (float*)alloc(64 * 256 * 4);
    u16* wi1b     = (u16*)alloc((size_t)256 * 128 * 2);       // Wi1 bf16 [256][128]
    u16* CT1      = (u16*)alloc((size_t)2 * 64 * 256 * 2);    // [L][64][256] bf16
    u16* CT2      = (u16*)alloc((size_t)2 * 64 * 256 * 2);
    float* cb1    = (float*)alloc((size_t)2 * 64 * 4);
    float* cb2    = (float*)alloc((size_t)2 * 64 * 4);
    float* wasb1  = (float*)alloc((size_t)2 * 64 * 4 * 4);    // [L][64][4]
    float* wadb1  = (float*)alloc((size_t)2 * 64 * 4 * 4);
    float* wasb2  = (float*)alloc((size_t)2 * 64 * 4 * 4);
    float* wadb2  = (float*)alloc((size_t)2 * 64 * 4 * 4);

    // CSR build (per snapshot, includes self-loops)
    k_fill1<<<(TT * NN + 255) / 256, 256, 0, stream>>>(csr_fil, TT * NN);
    k_count<<<(TT * EE + 255) / 256, 256, 0, stream>>>(edges, csr_fil);
    k_scan1<<<TT * NCH, 256, 0, stream>>>(csr_fil, scan_sum);
    k_scan2<<<TT, 256, 0, stream>>>(scan_sum, scan_bas, csr_off);
    k_scan3<<<TT * NCH, 256, 0, stream>>>(csr_fil, scan_bas, csr_off);
    k_csrfill<<<(TT * ET + 255) / 256, 256, 0, stream>>>(edges, csr_fil, csr_src);

    // weight preps
    k_transpose<<<(256 * 64 + 255) / 256, 256, 0, stream>>>(Wh1, WhT1, 256, 64);
    k_transpose<<<(256 * 64 + 255) / 256, 256, 0, stream>>>(Wi2, WiT2, 256, 64);
    k_transpose<<<(256 * 64 + 255) / 256, 256, 0, stream>>>(Wh2, WhT2, 256, 64);
    k_prep_wi1<<<(256 * 128 + 255) / 256, 256, 0, stream>>>(Wi1, wi1b);
    k_prep_was<<<2, 256, 0, stream>>>(g1W, g1as, g1ad, wasb1, wadb1);
    k_prep_was<<<2, 256, 0, stream>>>(g2W, g2as, g2ad, wasb2, wadb2);
    k_prep_cmb<<<(2 * 64 * 256 + 255) / 256, 256, 0, stream>>>(g1W, l1W, CT1);
    k_prep_cmb<<<(2 * 64 * 256 + 255) / 256, 256, 0, stream>>>(g2W, l2W, CT2);
    k_prep_cb<<<1, 256, 0, stream>>>(g1b, l1W, l1b, cb1);
    k_prep_cb<<<1, 256, 0, stream>>>(g2b, l2W, l2b, cb2);
    // emb -> bf16
    k_f2bf4<<<(TT * NN * 16 + 255) / 256, 256, 0, stream>>>(emb, embb, TT * NN * 16);

    for (int s = 0; s < 2; ++s) {
        const float* was = s ? wasb2 : wasb1;
        const float* wad = s ? wadb2 : wadb1;
        const u16* CT    = s ? CT2 : CT1;
        const float* cbp = s ? cb2 : cb1;
        for (int t = 0; t < TT; ++t) {
            for (int l = 0; l < 2; ++l) {
                const u16* xin = (l == 0) ? (embb + (size_t)t * NN * 64) : xbuf;
                k_alar_x<<<NN / 16, 256, 0, stream>>>(
                    xin, was + l * 256, wad + l * 256, albuf, arbuf);
                k_agg_x<<<NN / 4, 256, 0, stream>>>(
                    csr_off + (size_t)t * (NN + 1), csr_src + (size_t)t * ET,
                    albuf, arbuf, xin, xaggb);
                k_gemm_cmb<<<(NN + 63) / 64, 256, 0, stream>>>(
                    xaggb, CT + (size_t)l * 16384, cbp + l * 64, xbuf);
            }
            // seq2[t][row][s*64 .. s*64+63] = xbuf[clf[row]] (bf16)
            k_gather<<<(NC * 16 + 255) / 256, 256, 0, stream>>>(
                xbuf, clf, seq2 + (size_t)t * NC * 128 + s * 64);
        }
    }

    // LSTM1 x-gates for all steps: gx = seq2 @ Wi1^T  (M = TT*NC)
    k_gemm_gx<<<(TT * NC + 63) / 64, 256, 0, stream>>>(seq2, wi1b, gxb, TT * NC);

    // fused recurrent LSTM + FC, 4 rows/wave (2 waves/SIMD)
    k_lstm_fc<<<NC / 16, 256, 0, stream>>>(
        gxb, WhT1, b1, WiT2, WhT2, b2,
        fc1W, fc1b, fc2W, fc2b, (float*)d_out);
}

// Round 26
// 1694.570 us; speedup vs baseline: 1.0896x; 1.0368x over previous
//
#include <hip/hip_runtime.h>

#define NN 50000
#define TT 5
#define EE 500000
#define NC 8192
#define ET (EE + NN)
#define NCH 196   // ceil(NN/256)

typedef unsigned short u16;
typedef __attribute__((ext_vector_type(8))) short bf16x8;
typedef __attribute__((ext_vector_type(4))) float f32x4;

__device__ __forceinline__ float lrelu(float x) { return x >= 0.f ? x : 0.2f * x; }
__device__ __forceinline__ float sigm(float x) { return 1.f / (1.f + expf(-x)); }
__device__ __forceinline__ float bf2f(u16 u) {
    union { unsigned int i; float f; } v; v.i = ((unsigned int)u) << 16; return v.f;
}
__device__ __forceinline__ u16 f2bf(float f) {
    unsigned int x = __float_as_uint(f);
    return (u16)((x + 0x7fffu + ((x >> 16) & 1u)) >> 16);
}
__device__ __forceinline__ ushort4 f4tobf(float4 v) {
    ushort4 u; u.x = f2bf(v.x); u.y = f2bf(v.y); u.z = f2bf(v.z); u.w = f2bf(v.w);
    return u;
}
__device__ __forceinline__ float4 bf4tof(ushort4 u) {
    return make_float4(bf2f(u.x), bf2f(u.y), bf2f(u.z), bf2f(u.w));
}

// ---------------- CSR build ----------------
__global__ void k_fill1(int* p, int n) {
    int i = blockIdx.x * 256 + threadIdx.x;
    if (i < n) p[i] = 1;
}

__global__ void k_count(const int* __restrict__ edges, int* __restrict__ cnt) {
    int i = blockIdx.x * 256 + threadIdx.x;
    if (i >= TT * EE) return;
    int t = i / EE, e = i % EE;
    int dst = edges[(size_t)t * 2 * EE + EE + e];
    atomicAdd(&cnt[t * NN + dst], 1);
}

__global__ __launch_bounds__(256) void k_scan1(const int* __restrict__ cnt,
                                               int* __restrict__ sums) {
    int t = blockIdx.x / NCH, ch = blockIdx.x % NCH;
    int i = ch * 256 + threadIdx.x;
    int v = (i < NN) ? cnt[t * NN + i] : 0;
    __shared__ int s[256];
    s[threadIdx.x] = v;
    __syncthreads();
    for (int o = 128; o > 0; o >>= 1) {
        if (threadIdx.x < o) s[threadIdx.x] += s[threadIdx.x + o];
        __syncthreads();
    }
    if (threadIdx.x == 0) sums[t * NCH + ch] = s[0];
}

__global__ __launch_bounds__(256) void k_scan2(const int* __restrict__ sums,
                                               int* __restrict__ bases,
                                               int* __restrict__ off) {
    int t = blockIdx.x;
    __shared__ int s[256];
    int v = (threadIdx.x < NCH) ? sums[t * NCH + threadIdx.x] : 0;
    s[threadIdx.x] = v;
    __syncthreads();
    for (int o = 1; o < 256; o <<= 1) {
        int tv = (threadIdx.x >= o) ? s[threadIdx.x - o] : 0;
        __syncthreads();
        s[threadIdx.x] += tv;
        __syncthreads();
    }
    if (threadIdx.x < NCH) bases[t * NCH + threadIdx.x] = s[threadIdx.x] - v;
    if (threadIdx.x == 255) off[t * (NN + 1) + NN] = s[255];
}

__global__ __launch_bounds__(256) void k_scan3(int* __restrict__ cnt,
                                               const int* __restrict__ bases,
                                               int* __restrict__ off) {
    int t = blockIdx.x / NCH, ch = blockIdx.x % NCH;
    int i = ch * 256 + threadIdx.x;
    int v = (i < NN) ? cnt[t * NN + i] : 0;
    __shared__ int s[256];
    s[threadIdx.x] = v;
    __syncthreads();
    for (int o = 1; o < 256; o <<= 1) {
        int tv = (threadIdx.x >= o) ? s[threadIdx.x - o] : 0;
        __syncthreads();
        s[threadIdx.x] += tv;
        __syncthreads();
    }
    if (i < NN) {
        int excl = bases[t * NCH + ch] + s[threadIdx.x] - v;
        off[t * (NN + 1) + i] = excl;
        cnt[t * NN + i] = excl;  // becomes fill pointer
    }
}

__global__ void k_csrfill(const int* __restrict__ edges, int* __restrict__ fil,
                          int* __restrict__ csr) {
    int i = blockIdx.x * 256 + threadIdx.x;
    if (i >= TT * ET) return;
    int t = i / ET, r = i % ET;
    int src, dst;
    if (r < EE) {
        src = edges[(size_t)t * 2 * EE + r];
        dst = edges[(size_t)t * 2 * EE + EE + r];
    } else {
        src = dst = r - EE;
    }
    int pos = atomicAdd(&fil[t * NN + dst], 1);
    csr[(size_t)t * ET + pos] = src;
}

// ---------------- prep ----------------
__global__ void k_transpose(const float* __restrict__ src, float* __restrict__ dst,
                            int R, int C) {
    int i = blockIdx.x * 256 + threadIdx.x;
    if (i >= R * C) return;
    int r = i / C, c = i % C;
    dst[c * R + r] = src[i];
}

// Wi1 [256][128] f32 -> bf16 (already gate-major, k-contiguous = MFMA B format)
__global__ void k_prep_wi1(const float* __restrict__ W, u16* __restrict__ Wb) {
    int i = blockIdx.x * 256 + threadIdx.x;
    if (i >= 256 * 128) return;
    Wb[i] = f2bf(W[i]);
}

// was/wad[l][k][hd] = sum_f W[l][k][hd*64+f] * a[l][hd][f]   (f32-exact)
__global__ void k_prep_was(const float* __restrict__ W,
                           const float* __restrict__ as_,
                           const float* __restrict__ ad_,
                           float* __restrict__ was, float* __restrict__ wad) {
    int id = blockIdx.x * 256 + threadIdx.x;
    if (id >= 2 * 64 * 4) return;
    int l = id >> 8, rem = id & 255;
    int k = rem >> 2, hd = rem & 3;
    float s = 0.f, d = 0.f;
    for (int f = 0; f < 64; ++f) {
        float w = W[(size_t)l * 16384 + k * 256 + hd * 64 + f];
        s += w * as_[l * 256 + hd * 64 + f];
        d += w * ad_[l * 256 + hd * 64 + f];
    }
    was[l * 256 + k * 4 + hd] = s;
    wad[l * 256 + k * 4 + hd] = d;
}

// Combined C^T[l][f][kk] = sum_j W[l][k][hd*64+j] * lW[l][hd*64+j][f], kk=hd*64+k
__global__ void k_prep_cmb(const float* __restrict__ W, const float* __restrict__ lW,
                           u16* __restrict__ CT) {
    int i = blockIdx.x * 256 + threadIdx.x;
    if (i >= 2 * 64 * 256) return;
    int l = i >> 14, rem = i & 16383;
    int f = rem >> 8, kk = rem & 255;
    int hd = kk >> 6, k = kk & 63;
    float s = 0.f;
    for (int j = 0; j < 64; ++j)
        s += W[(size_t)l * 16384 + k * 256 + hd * 64 + j] *
             lW[(size_t)l * 16384 + (hd * 64 + j) * 64 + f];
    CT[(size_t)l * 16384 + f * 256 + kk] = f2bf(s);
}

// cb[l][f] = sum_j gb[l][j]*lW[l][j][f] + lb[l][f]
__global__ void k_prep_cb(const float* __restrict__ gb, const float* __restrict__ lW,
                          const float* __restrict__ lb, float* __restrict__ cb) {
    int i = blockIdx.x * 256 + threadIdx.x;
    if (i >= 2 * 64) return;
    int l = i >> 6, f = i & 63;
    float s = lb[l * 64 + f];
    for (int j = 0; j < 256; ++j)
        s += gb[l * 256 + j] * lW[(size_t)l * 16384 + j * 64 + f];
    cb[l * 64 + f] = s;
}

// f32 -> bf16 bulk convert (float4 -> ushort4)
__global__ void k_f2bf4(const float* __restrict__ src, u16* __restrict__ dst, int n4) {
    int i = blockIdx.x * 256 + threadIdx.x;
    if (i >= n4) return;
    float4 f = ((const float4*)src)[i];
    ((ushort4*)dst)[i] = f4tobf(f);
}

// gather bf16 rows into seq2 [row][128] at column offset held in dst base
__global__ void k_gather(const u16* __restrict__ x, const int* __restrict__ clf,
                         u16* __restrict__ dst) {
    int i = blockIdx.x * 256 + threadIdx.x;
    if (i >= NC * 16) return;
    int row = i >> 4, c4 = i & 15;
    int node = clf[row];
    ushort4 u = ((const ushort4*)x)[(size_t)node * 16 + c4];
    *(ushort4*)&dst[(size_t)row * 128 + c4 * 4] = u;
}

// ---------------- al/ar: x[M,64] dot was/wad[64][4] (M rows, batched) --------
__global__ __launch_bounds__(256) void k_alar_x(const u16* __restrict__ xb,
                                                const float* __restrict__ was,
                                                const float* __restrict__ wad,
                                                float* __restrict__ al,
                                                float* __restrict__ ar) {
    int lane = threadIdx.x & 63;
    int n = blockIdx.x * 16 + (threadIdx.x >> 6) * 4 + (lane >> 4);
    int q = lane & 15;
    ushort4 u = *(const ushort4*)&xb[(size_t)n * 64 + q * 4];
    float ps[4] = {0.f, 0.f, 0.f, 0.f};
    float pd[4] = {0.f, 0.f, 0.f, 0.f};
#pragma unroll
    for (int d = 0; d < 4; ++d) {
        u16 uv = (d == 0) ? u.x : (d == 1) ? u.y : (d == 2) ? u.z : u.w;
        float xv = bf2f(uv);
        int k = q * 4 + d;
        float4 w4 = *(const float4*)&was[k * 4];
        float4 d4 = *(const float4*)&wad[k * 4];
        ps[0] += xv * w4.x; ps[1] += xv * w4.y;
        ps[2] += xv * w4.z; ps[3] += xv * w4.w;
        pd[0] += xv * d4.x; pd[1] += xv * d4.y;
        pd[2] += xv * d4.z; pd[3] += xv * d4.w;
    }
#pragma unroll
    for (int o = 1; o < 16; o <<= 1) {
#pragma unroll
        for (int hd = 0; hd < 4; ++hd) {
            ps[hd] += __shfl_xor(ps[hd], o, 64);
            pd[hd] += __shfl_xor(pd[hd], o, 64);
        }
    }
    if (q == 0) {
        *(float4*)&al[n * 4] = make_float4(ps[0], ps[1], ps[2], ps[3]);
        *(float4*)&ar[n * 4] = make_float4(pd[0], pd[1], pd[2], pd[3]);
    }
}

// ---------------- attention aggregation over x, 2 edges/round, 4-deep pipeline ----
// (R17-verified best variant)
__global__ __launch_bounds__(256) void k_agg_x(const int* __restrict__ off,
                                               const int* __restrict__ csr,
                                               const float* __restrict__ al,
                                               const float* __restrict__ ar,
                                               const u16* __restrict__ xb,
                                               u16* __restrict__ xagg) {
    int lane = threadIdx.x & 63;
    int n = blockIdx.x * 4 + (threadIdx.x >> 6);
    int hh = lane & 3;
    int hf = lane >> 5;          // 0 = even edge of round, 1 = odd edge
    int kd = lane & 31;          // dim-pair index: dims 2kd, 2kd+1
    float ar_hh = ar[n * 4 + hh];
    int beg = off[n], end = off[n + 1];
    float den[4]  = {0.f, 0.f, 0.f, 0.f};
    float accL[4] = {0.f, 0.f, 0.f, 0.f};
    float accH[4] = {0.f, 0.f, 0.f, 0.f};

    for (int cbase = beg; cbase < end; cbase += 64) {
        int cnt = min(64, end - cbase);
        int sidx = csr[cbase + ((lane < cnt) ? lane : 0)];
        int nbat = (cnt + 15) >> 4;
        float pb[4];
#pragma unroll
        for (int b = 0; b < 4; ++b) {
            if (b < nbat) {
                int jj = b * 16 + (lane >> 2);
                int sj = __shfl(sidx, (jj < cnt) ? jj : 0, 64);
                pb[b] = expf(lrelu(al[sj * 4 + hh] + ar_hh));
            } else {
                pb[b] = 0.f;
            }
        }
        int R = (cnt + 1) >> 1;   // rounds of 2 edges

#define LDX(r, dstv)                                                         \
        {                                                                    \
            int jj_ = (r) * 2 + hf;                                          \
            int ss_ = __shfl(sidx, (jj_ < cnt) ? jj_ : 0, 64);               \
            dstv = *(const unsigned*)&xb[(size_t)ss_ * 64 + kd * 2];         \
        }
#define CONS(r, cv)                                                          \
        {                                                                    \
            int je_ = (r) * 2 + hf;                                          \
            int b_ = ((r) >> 3) & 3;                                         \
            float pbb_ = (b_ == 0) ? pb[0] : (b_ == 1) ? pb[1]               \
                        : (b_ == 2) ? pb[2] : pb[3];                         \
            float xlo_ = bf2f((u16)((cv) & 0xffffu));                        \
            float xhi_ = bf2f((u16)((cv) >> 16));                            \
            _Pragma("unroll")                                                \
            for (int hd_ = 0; hd_ < 4; ++hd_) {                              \
                float p_ = __shfl(pbb_, ((je_ & 15) << 2) | hd_, 64);        \
                p_ = (je_ < cnt) ? p_ : 0.f;                                 \
                accL[hd_] += p_ * xlo_;                                      \
                accH[hd_] += p_ * xhi_;                                      \
                den[hd_]  += p_;                                             \
            }                                                                \
        }

        unsigned c0, c1, c2, c3;
        LDX(0, c0); LDX(1, c1); LDX(2, c2); LDX(3, c3);
        for (int g = 0; g < R; g += 4) {
            unsigned n0 = 0, n1 = 0, n2 = 0, n3 = 0;
            if (g + 4 < R) {          // wave-uniform
                LDX(g + 4, n0); LDX(g + 5, n1); LDX(g + 6, n2); LDX(g + 7, n3);
            }
            CONS(g + 0, c0);
            if (g + 1 < R) CONS(g + 1, c1);
            if (g + 2 < R) CONS(g + 2, c2);
            if (g + 3 < R) CONS(g + 3, c3);
            c0 = n0; c1 = n1; c2 = n2; c3 = n3;
        }
#undef LDX
#undef CONS
    }
    // merge even/odd halves
#pragma unroll
    for (int hd = 0; hd < 4; ++hd) {
        accL[hd] += __shfl_xor(accL[hd], 32, 64);
        accH[hd] += __shfl_xor(accH[hd], 32, 64);
        den[hd]  += __shfl_xor(den[hd], 32, 64);
    }
    if (hf == 0) {
#pragma unroll
        for (int hd = 0; hd < 4; ++hd) {
            float inv = 1.f / (den[hd] + 1e-16f);
            unsigned w = (unsigned)f2bf(accL[hd] * inv) |
                         ((unsigned)f2bf(accH[hd] * inv) << 16);
            *(unsigned*)&xagg[(size_t)n * 256 + hd * 64 + kd * 2] = w;
        }
    }
}

// out[N,64](bf16) = relu(A[N,256](bf16) @ C[256,64] + cb)  -- MFMA 16x16x32
// Optional fused alar: al/ar of the OUTPUT rows (next layer's logits) from the
// pre-bf16-rounding f32 values. was2/wad2 are [64][4]; reduction over the 16
// c-lanes of each g-group (xor strides 1,2,4,8 stay in-group).
__global__ __launch_bounds__(256) void k_gemm_cmb(const u16* __restrict__ A,
                                                  const u16* __restrict__ CT,
                                                  const float* __restrict__ cb,
                                                  u16* __restrict__ out,
                                                  const float* __restrict__ was2,
                                                  const float* __restrict__ wad2,
                                                  float* __restrict__ al1,
                                                  float* __restrict__ ar1) {
    int lane = threadIdx.x & 63;
    int wid = threadIdx.x >> 6;
    int g = lane >> 4, c = lane & 15;
    int r0 = blockIdx.x * 64 + wid * 16;
    int arow = r0 + c; if (arow > NN - 1) arow = NN - 1;
    const u16* aptr = A + (size_t)arow * 256 + g * 8;
    const u16* bptr = CT + (size_t)c * 256 + g * 8;
    f32x4 acc[4];
#pragma unroll
    for (int t = 0; t < 4; ++t) acc[t] = (f32x4){0.f, 0.f, 0.f, 0.f};
#pragma unroll
    for (int ks = 0; ks < 8; ++ks) {
        bf16x8 af = *(const bf16x8*)(aptr + ks * 32);
#pragma unroll
        for (int t = 0; t < 4; ++t) {
            bf16x8 bfr = *(const bf16x8*)(bptr + t * 16 * 256 + ks * 32);
            acc[t] = __builtin_amdgcn_mfma_f32_16x16x32_bf16(af, bfr, acc[t], 0, 0, 0);
        }
    }
    int orow0 = r0 + g * 4;
    float ps[4][4], pd[4][4];
#pragma unroll
    for (int j = 0; j < 4; ++j)
#pragma unroll
        for (int hd = 0; hd < 4; ++hd) { ps[j][hd] = 0.f; pd[j][hd] = 0.f; }
#pragma unroll
    for (int t = 0; t < 4; ++t) {
        int col = t * 16 + c;
        float bv = cb[col];
        float4 w4 = make_float4(0.f, 0.f, 0.f, 0.f), d4 = w4;
        if (al1) {
            w4 = *(const float4*)&was2[col * 4];
            d4 = *(const float4*)&wad2[col * 4];
        }
#pragma unroll
        for (int j = 0; j < 4; ++j) {
            int row = orow0 + j;
            float o = fmaxf(acc[t][j] + bv, 0.f);
            if (row < NN) out[(size_t)row * 64 + col] = f2bf(o);
            if (al1) {
                ps[j][0] += o * w4.x; ps[j][1] += o * w4.y;
                ps[j][2] += o * w4.z; ps[j][3] += o * w4.w;
                pd[j][0] += o * d4.x; pd[j][1] += o * d4.y;
                pd[j][2] += o * d4.z; pd[j][3] += o * d4.w;
            }
        }
    }
    if (al1) {
#pragma unroll
        for (int o = 1; o < 16; o <<= 1) {
#pragma unroll
            for (int j = 0; j < 4; ++j) {
#pragma unroll
                for (int hd = 0; hd < 4; ++hd) {
                    ps[j][hd] += __shfl_xor(ps[j][hd], o, 64);
                    pd[j][hd] += __shfl_xor(pd[j][hd], o, 64);
                }
            }
        }
        if (c == 0) {
#pragma unroll
            for (int j = 0; j < 4; ++j) {
                int row = orow0 + j;
                if (row < NN) {
                    *(float4*)&al1[row * 4] = make_float4(ps[j][0], ps[j][1], ps[j][2], ps[j][3]);
                    *(float4*)&ar1[row * 4] = make_float4(pd[j][0], pd[j][1], pd[j][2], pd[j][3]);
                }
            }
        }
    }
}

// gx[M][256] = seq2[M][128](bf16) @ Wi1^T (Wi1b [256][128] bf16)  -- MFMA
__global__ __launch_bounds__(256) void k_gemm_gx(const u16* __restrict__ A,
                                                 const u16* __restrict__ BT,
                                                 float* __restrict__ gxout, int M) {
    int lane = threadIdx.x & 63;
    int wid = threadIdx.x >> 6;
    int g = lane >> 4, c = lane & 15;
    int r0 = blockIdx.x * 64 + wid * 16;
    int arow = r0 + c; if (arow > M - 1) arow = M - 1;
    const u16* aptr = A + (size_t)arow * 128 + g * 8;
    f32x4 acc[16];
#pragma unroll
    for (int t = 0; t < 16; ++t) acc[t] = (f32x4){0.f, 0.f, 0.f, 0.f};
#pragma unroll
    for (int ks = 0; ks < 4; ++ks) {
        bf16x8 af = *(const bf16x8*)(aptr + ks * 32);
#pragma unroll
        for (int t = 0; t < 16; ++t) {
            bf16x8 bfr = *(const bf16x8*)(BT + (size_t)(t * 16 + c) * 128 + ks * 32 + g * 8);
            acc[t] = __builtin_amdgcn_mfma_f32_16x16x32_bf16(af, bfr, acc[t], 0, 0, 0);
        }
    }
#pragma unroll
    for (int t = 0; t < 16; ++t) {
#pragma unroll
        for (int j = 0; j < 4; ++j) {
            int row = r0 + g * 4 + j;
            if (row < M) gxout[(size_t)row * 256 + t * 16 + c] = acc[t][j];
        }
    }
}

// ---------------- fused LSTM (recurrent part only) + FC, 4 rows/wave ---------
__global__ __launch_bounds__(256) void k_lstm_fc(const float* __restrict__ gx,
                                                 const float* __restrict__ WhT1,
                                                 const float* __restrict__ bb1,
                                                 const float* __restrict__ WiT2,
                                                 const float* __restrict__ WhT2,
                                                 const float* __restrict__ bb2,
                                                 const float* __restrict__ fw1,
                                                 const float* __restrict__ fb1,
                                                 const float* __restrict__ fw2,
                                                 const float* __restrict__ fb2,
                                                 float* __restrict__ out) {
    __shared__ float xs[4][4][128];
    int w = threadIdx.x >> 6, lane = threadIdx.x & 63;
    int row0 = blockIdx.x * 16 + w * 4;
    float h1[4], c1[4], h2[4], c2[4];
#pragma unroll
    for (int r = 0; r < 4; ++r) { h1[r] = 0.f; c1[r] = 0.f; h2[r] = 0.f; c2[r] = 0.f; }
    float bi1 = bb1[lane], bf1 = bb1[64 + lane], bg1 = bb1[128 + lane], bo1 = bb1[192 + lane];
    float bi2 = bb2[lane], bf2v = bb2[64 + lane], bg2 = bb2[128 + lane], bo2 = bb2[192 + lane];

    for (int st = 0; st < TT; ++st) {
        int tsn = TT - 1 - st;   // outs[::-1]
        // ---- LSTM1: gates = gx + Wh1 @ h1 + b
#pragma unroll
        for (int r = 0; r < 4; ++r) xs[w][r][lane] = h1[r];
        __syncthreads();
        {
            const float* gxp = gx + (size_t)tsn * NC * 256;
            float ai[4], af[4], ag[4], ao[4];
#pragma unroll
            for (int r = 0; r < 4; ++r) {
                const float* gr = gxp + (size_t)(row0 + r) * 256;
                ai[r] = bi1 + gr[lane];
                af[r] = bf1 + gr[64 + lane];
                ag[r] = bg1 + gr[128 + lane];
                ao[r] = bo1 + gr[192 + lane];
            }
            for (int k = 0; k < 64; ++k) {
                const float* wr = &WhT1[k * 256];
                float wi = wr[lane], wf = wr[64 + lane], wg = wr[128 + lane], wo = wr[192 + lane];
#pragma unroll
                for (int r = 0; r < 4; ++r) {
                    float hv = xs[w][r][k];
                    ai[r] += hv * wi; af[r] += hv * wf;
                    ag[r] += hv * wg; ao[r] += hv * wo;
                }
            }
#pragma unroll
            for (int r = 0; r < 4; ++r) {
                c1[r] = sigm(af[r]) * c1[r] + sigm(ai[r]) * tanhf(ag[r]);
                h1[r] = sigm(ao[r]) * tanhf(c1[r]);
            }
        }
        __syncthreads();
        // ---- LSTM2: x = h1 (64), h = h2
#pragma unroll
        for (int r = 0; r < 4; ++r) {
            xs[w][r][lane]      = h1[r];
            xs[w][r][64 + lane] = h2[r];
        }
        __syncthreads();
        {
            float ai[4], af[4], ag[4], ao[4];
#pragma unroll
            for (int r = 0; r < 4; ++r) { ai[r] = bi2; af[r] = bf2v; ag[r] = bg2; ao[r] = bo2; }
            for (int k = 0; k < 64; ++k) {
                const float* wr = &WiT2[k * 256];
                float wi = wr[lane], wf = wr[64 + lane], wg = wr[128 + lane], wo = wr[192 + lane];
#pragma unroll
                for (int r = 0; r < 4; ++r) {
                    float xv = xs[w][r][k];
                    ai[r] += xv * wi; af[r] += xv * wf;
                    ag[r] += xv * wg; ao[r] += xv * wo;
                }
            }
            for (int k = 0; k < 64; ++k) {
                const float* wr = &WhT2[k * 256];
                float wi = wr[lane], wf = wr[64 + lane], wg = wr[128 + lane], wo = wr[192 + lane];
#pragma unroll
                for (int r = 0; r < 4; ++r) {
                    float hv = xs[w][r][64 + k];
                    ai[r] += hv * wi; af[r] += hv * wf;
                    ag[r] += hv * wg; ao[r] += hv * wo;
                }
            }
#pragma unroll
            for (int r = 0; r < 4; ++r) {
                c2[r] = sigm(af[r]) * c2[r] + sigm(ai[r]) * tanhf(ag[r]);
                h2[r] = sigm(ao[r]) * tanhf(c2[r]);
            }
        }
        __syncthreads();
    }
    // ---- FC head: z = [h1 | h2]
#pragma unroll
    for (int r = 0; r < 4; ++r) {
        xs[w][r][lane]      = h1[r];
        xs[w][r][64 + lane] = h2[r];
    }
    __syncthreads();
    float acc[4];
#pragma unroll
    for (int r = 0; r < 4; ++r) acc[r] = fb1[lane];
    for (int k = 0; k < 128; ++k) {
        float wv = fw1[k * 64 + lane];
#pragma unroll
        for (int r = 0; r < 4; ++r) acc[r] += xs[w][r][k] * wv;
    }
    float w20 = fw2[lane * 2], w21 = fw2[lane * 2 + 1];
#pragma unroll
    for (int r = 0; r < 4; ++r) {
        float rr = fmaxf(acc[r], 0.f);
        float t0 = rr * w20;
        float t1 = rr * w21;
#pragma unroll
        for (int o = 32; o >= 1; o >>= 1) {
            t0 += __shfl_xor(t0, o, 64);
            t1 += __shfl_xor(t1, o, 64);
        }
        if (lane == 0) {
            out[(row0 + r) * 2]     = fmaxf(t0 + fb2[0], 0.f);
            out[(row0 + r) * 2 + 1] = fmaxf(t1 + fb2[1], 0.f);
        }
    }
}

extern "C" void kernel_launch(void* const* d_in, const int* in_sizes, int n_in,
                              void* d_out, int out_size, void* d_ws, size_t ws_size,
                              hipStream_t stream) {
    const float* emb  = (const float*)d_in[0];
    const float* g1W  = (const float*)d_in[1];
    const float* g1as = (const float*)d_in[2];
    const float* g1ad = (const float*)d_in[3];
    const float* g1b  = (const float*)d_in[4];
    const float* l1W  = (const float*)d_in[5];
    const float* l1b  = (const float*)d_in[6];
    const float* g2W  = (const float*)d_in[7];
    const float* g2as = (const float*)d_in[8];
    const float* g2ad = (const float*)d_in[9];
    const float* g2b  = (const float*)d_in[10];
    const float* l2W  = (const float*)d_in[11];
    const float* l2b  = (const float*)d_in[12];
    const float* Wi1  = (const float*)d_in[13];
    const float* Wh1  = (const float*)d_in[14];
    const float* b1   = (const float*)d_in[15];
    const float* Wi2  = (const float*)d_in[16];
    const float* Wh2  = (const float*)d_in[17];
    const float* b2   = (const float*)d_in[18];
    const float* fc1W = (const float*)d_in[19];
    const float* fc1b = (const float*)d_in[20];
    const float* fc2W = (const float*)d_in[21];
    const float* fc2b = (const float*)d_in[22];
    const int* edges = (const int*)d_in[23];
    const int* clf   = (const int*)d_in[27];

    char* ws = (char*)d_ws;
    size_t woff = 0;
    auto alloc = [&](size_t bytes) -> void* {
        void* p = ws + woff;
        woff += (bytes + 255) & ~(size_t)255;
        return p;
    };
    int* csr_off  = (int*)alloc((size_t)TT * (NN + 1) * 4);
    int* csr_fil  = (int*)alloc((size_t)TT * NN * 4);
    int* csr_src  = (int*)alloc((size_t)TT * ET * 4);
    int* scan_sum = (int*)alloc((size_t)TT * NCH * 4);
    int* scan_bas = (int*)alloc((size_t)TT * NCH * 4);
    u16* embb     = (u16*)alloc((size_t)TT * NN * 64 * 2);
    u16* xbuf     = (u16*)alloc((size_t)NN * 64 * 2);
    u16* xaggb    = (u16*)alloc((size_t)NN * 256 * 2);
    float* al0    = (float*)alloc((size_t)TT * NN * 4 * 4);   // batched embb alar
    float* ar0    = (float*)alloc((size_t)TT * NN * 4 * 4);
    float* al1    = (float*)alloc((size_t)NN * 4 * 4);        // fused from gemm_cmb(l=0)
    float* ar1    = (float*)alloc((size_t)NN * 4 * 4);
    u16* seq2     = (u16*)alloc((size_t)TT * NC * 128 * 2);   // [t][row][e1|e2] bf16
    float* gxb    = (float*)alloc((size_t)TT * NC * 256 * 4); // LSTM1 x-gates
    float* WhT1   = (float*)alloc(64 * 256 * 4);
    float* WiT2   = (float*)alloc(64 * 256 * 4);
    float* WhT2   = (float*)alloc(64 * 256 * 4);
    u16* wi1b     = (u16*)alloc((size_t)256 * 128 * 2);       // Wi1 bf16 [256][128]
    u16* CT1      = (u16*)alloc((size_t)2 * 64 * 256 * 2);    // [L][64][256] bf16
    u16* CT2      = (u16*)alloc((size_t)2 * 64 * 256 * 2);
    float* cb1    = (float*)alloc((size_t)2 * 64 * 4);
    float* cb2    = (float*)alloc((size_t)2 * 64 * 4);
    float* wasb1  = (float*)alloc((size_t)2 * 64 * 4 * 4);    // [L][64][4]
    float* wadb1  = (float*)alloc((size_t)2 * 64 * 4 * 4);
    float* wasb2  = (float*)alloc((size_t)2 * 64 * 4 * 4);
    float* wadb2  = (float*)alloc((size_t)2 * 64 * 4 * 4);

    // CSR build (per snapshot, includes self-loops)
    k_fill1<<<(TT * NN + 255) / 256, 256, 0, stream>>>(csr_fil, TT * NN);
    k_count<<<(TT * EE + 255) / 256, 256, 0, stream>>>(edges, csr_fil);
    k_scan1<<<TT * NCH, 256, 0, stream>>>(csr_fil, scan_sum);
    k_scan2<<<TT, 256, 0, stream>>>(scan_sum, scan_bas, csr_off);
    k_scan3<<<TT * NCH, 256, 0, stream>>>(csr_fil, scan_bas, csr_off);
    k_csrfill<<<(TT * ET + 255) / 256, 256, 0, stream>>>(edges, csr_fil, csr_src);

    // weight preps
    k_transpose<<<(256 * 64 + 255) / 256, 256, 0, stream>>>(Wh1, WhT1, 256, 64);
    k_transpose<<<(256 * 64 + 255) / 256, 256, 0, stream>>>(Wi2, WiT2, 256, 64);
    k_transpose<<<(256 * 64 + 255) / 256, 256, 0, stream>>>(Wh2, WhT2, 256, 64);
    k_prep_wi1<<<(256 * 128 + 255) / 256, 256, 0, stream>>>(Wi1, wi1b);
    k_prep_was<<<2, 256, 0, stream>>>(g1W, g1as, g1ad, wasb1, wadb1);
    k_prep_was<<<2, 256, 0, stream>>>(g2W, g2as, g2ad, wasb2, wadb2);
    k_prep_cmb<<<(2 * 64 * 256 + 255) / 256, 256, 0, stream>>>(g1W, l1W, CT1);
    k_prep_cmb<<<(2 * 64 * 256 + 255) / 256, 256, 0, stream>>>(g2W, l2W, CT2);
    k_prep_cb<<<1, 256, 0, stream>>>(g1b, l1W, l1b, cb1);
    k_prep_cb<<<1, 256, 0, stream>>>(g2b, l2W, l2b, cb2);
    // emb -> bf16
    k_f2bf4<<<(TT * NN * 16 + 255) / 256, 256, 0, stream>>>(emb, embb, TT * NN * 16);

    for (int s = 0; s < 2; ++s) {
        const float* was = s ? wasb2 : wasb1;
        const float* wad = s ? wadb2 : wadb1;
        const u16* CT    = s ? CT2 : CT1;
        const float* cbp = s ? cb2 : cb1;
        // batched alar over all TT snapshots of embb (layer 0 of this stack)
        k_alar_x<<<(TT * NN) / 16, 256, 0, stream>>>(
            embb, was + 0 * 256, wad + 0 * 256, al0, ar0);
        for (int t = 0; t < TT; ++t) {
            // ---- layer 0: input embb[t], al/ar from batched buffers; fused alar
            //      for layer 1 (was[l=1]) computed in the GEMM epilogue.
            k_agg_x<<<NN / 4, 256, 0, stream>>>(
                csr_off + (size_t)t * (NN + 1), csr_src + (size_t)t * ET,
                al0 + (size_t)t * NN * 4, ar0 + (size_t)t * NN * 4,
                embb + (size_t)t * NN * 64, xaggb);
            k_gemm_cmb<<<(NN + 63) / 64, 256, 0, stream>>>(
                xaggb, CT + (size_t)0 * 16384, cbp + 0 * 64, xbuf,
                was + 1 * 256, wad + 1 * 256, al1, ar1);
            // ---- layer 1: input xbuf, al/ar from fused epilogue
            k_agg_x<<<NN / 4, 256, 0, stream>>>(
                csr_off + (size_t)t * (NN + 1), csr_src + (size_t)t * ET,
                al1, ar1, xbuf, xaggb);
            k_gemm_cmb<<<(NN + 63) / 64, 256, 0, stream>>>(
                xaggb, CT + (size_t)1 * 16384, cbp + 1 * 64, xbuf,
                nullptr, nullptr, nullptr, nullptr);
            // seq2[t][row][s*64 .. s*64+63] = xbuf[clf[row]] (bf16)
            k_gather<<<(NC * 16 + 255) / 256, 256, 0, stream>>>(
                xbuf, clf, seq2 + (size_t)t * NC * 128 + s * 64);
        }
    }

    // LSTM1 x-gates for all steps: gx = seq2 @ Wi1^T  (M = TT*NC)
    k_gemm_gx<<<(TT * NC + 63) / 64, 256, 0, stream>>>(seq2, wi1b, gxb, TT * NC);

    // fused recurrent LSTM + FC, 4 rows/wave (2 waves/SIMD)
    k_lstm_fc<<<NC / 16, 256, 0, stream>>>(
        gxb, WhT1, b1, WiT2, WhT2, b2,
        fc1W, fc1b, fc2W, fc2b, (float*)d_out);
}

// Round 28
// 1458.563 us; speedup vs baseline: 1.2659x; 1.1618x over previous
//
#include <hip/hip_runtime.h>

#define NN 50000
#define TT 5
#define EE 500000
#define NC 8192
#define ET (EE + NN)
#define NCH 196   // ceil(NN/256)

typedef unsigned short u16;
typedef __attribute__((ext_vector_type(8))) short bf16x8;
typedef __attribute__((ext_vector_type(4))) float f32x4;

__device__ __forceinline__ float lrelu(float x) { return x >= 0.f ? x : 0.2f * x; }
__device__ __forceinline__ float sigm(float x) { return 1.f / (1.f + expf(-x)); }
__device__ __forceinline__ float bf2f(u16 u) {
    union { unsigned int i; float f; } v; v.i = ((unsigned int)u) << 16; return v.f;
}
__device__ __forceinline__ u16 f2bf(float f) {
    unsigned int x = __float_as_uint(f);
    return (u16)((x + 0x7fffu + ((x >> 16) & 1u)) >> 16);
}
__device__ __forceinline__ ushort4 f4tobf(float4 v) {
    ushort4 u; u.x = f2bf(v.x); u.y = f2bf(v.y); u.z = f2bf(v.z); u.w = f2bf(v.w);
    return u;
}
__device__ __forceinline__ float4 bf4tof(ushort4 u) {
    return make_float4(bf2f(u.x), bf2f(u.y), bf2f(u.z), bf2f(u.w));
}

// ---------------- CSR build ----------------
__global__ void k_fill1(int* p, int n) {
    int i = blockIdx.x * 256 + threadIdx.x;
    if (i < n) p[i] = 1;
}

__global__ void k_count(const int* __restrict__ edges, int* __restrict__ cnt) {
    int i = blockIdx.x * 256 + threadIdx.x;
    if (i >= TT * EE) return;
    int t = i / EE, e = i % EE;
    int dst = edges[(size_t)t * 2 * EE + EE + e];
    atomicAdd(&cnt[t * NN + dst], 1);
}

__global__ __launch_bounds__(256) void k_scan1(const int* __restrict__ cnt,
                                               int* __restrict__ sums) {
    int t = blockIdx.x / NCH, ch = blockIdx.x % NCH;
    int i = ch * 256 + threadIdx.x;
    int v = (i < NN) ? cnt[t * NN + i] : 0;
    __shared__ int s[256];
    s[threadIdx.x] = v;
    __syncthreads();
    for (int o = 128; o > 0; o >>= 1) {
        if (threadIdx.x < o) s[threadIdx.x] += s[threadIdx.x + o];
        __syncthreads();
    }
    if (threadIdx.x == 0) sums[t * NCH + ch] = s[0];
}

__global__ __launch_bounds__(256) void k_scan2(const int* __restrict__ sums,
                                               int* __restrict__ bases,
                                               int* __restrict__ off) {
    int t = blockIdx.x;
    __shared__ int s[256];
    int v = (threadIdx.x < NCH) ? sums[t * NCH + threadIdx.x] : 0;
    s[threadIdx.x] = v;
    __syncthreads();
    for (int o = 1; o < 256; o <<= 1) {
        int tv = (threadIdx.x >= o) ? s[threadIdx.x - o] : 0;
        __syncthreads();
        s[threadIdx.x] += tv;
        __syncthreads();
    }
    if (threadIdx.x < NCH) bases[t * NCH + threadIdx.x] = s[threadIdx.x] - v;
    if (threadIdx.x == 255) off[t * (NN + 1) + NN] = s[255];
}

__global__ __launch_bounds__(256) void k_scan3(int* __restrict__ cnt,
                                               const int* __restrict__ bases,
                                               int* __restrict__ off) {
    int t = blockIdx.x / NCH, ch = blockIdx.x % NCH;
    int i = ch * 256 + threadIdx.x;
    int v = (i < NN) ? cnt[t * NN + i] : 0;
    __shared__ int s[256];
    s[threadIdx.x] = v;
    __syncthreads();
    for (int o = 1; o < 256; o <<= 1) {
        int tv = (threadIdx.x >= o) ? s[threadIdx.x - o] : 0;
        __syncthreads();
        s[threadIdx.x] += tv;
        __syncthreads();
    }
    if (i < NN) {
        int excl = bases[t * NCH + ch] + s[threadIdx.x] - v;
        off[t * (NN + 1) + i] = excl;
        cnt[t * NN + i] = excl;  // becomes fill pointer
    }
}

__global__ void k_csrfill(const int* __restrict__ edges, int* __restrict__ fil,
                          int* __restrict__ csr) {
    int i = blockIdx.x * 256 + threadIdx.x;
    if (i >= TT * ET) return;
    int t = i / ET, r = i % ET;
    int src, dst;
    if (r < EE) {
        src = edges[(size_t)t * 2 * EE + r];
        dst = edges[(size_t)t * 2 * EE + EE + r];
    } else {
        src = dst = r - EE;
    }
    int pos = atomicAdd(&fil[t * NN + dst], 1);
    csr[(size_t)t * ET + pos] = src;
}

// ---------------- prep ----------------
__global__ void k_transpose(const float* __restrict__ src, float* __restrict__ dst,
                            int R, int C) {
    int i = blockIdx.x * 256 + threadIdx.x;
    if (i >= R * C) return;
    int r = i / C, c = i % C;
    dst[c * R + r] = src[i];
}

// Wi1 [256][128] f32 -> bf16 (already gate-major, k-contiguous = MFMA B format)
__global__ void k_prep_wi1(const float* __restrict__ W, u16* __restrict__ Wb) {
    int i = blockIdx.x * 256 + threadIdx.x;
    if (i >= 256 * 128) return;
    Wb[i] = f2bf(W[i]);
}

// was/wad[l][k][hd] = sum_f W[l][k][hd*64+f] * a[l][hd][f]   (f32-exact)
__global__ void k_prep_was(const float* __restrict__ W,
                           const float* __restrict__ as_,
                           const float* __restrict__ ad_,
                           float* __restrict__ was, float* __restrict__ wad) {
    int id = blockIdx.x * 256 + threadIdx.x;
    if (id >= 2 * 64 * 4) return;
    int l = id >> 8, rem = id & 255;
    int k = rem >> 2, hd = rem & 3;
    float s = 0.f, d = 0.f;
    for (int f = 0; f < 64; ++f) {
        float w = W[(size_t)l * 16384 + k * 256 + hd * 64 + f];
        s += w * as_[l * 256 + hd * 64 + f];
        d += w * ad_[l * 256 + hd * 64 + f];
    }
    was[l * 256 + k * 4 + hd] = s;
    wad[l * 256 + k * 4 + hd] = d;
}

// Combined C^T[l][f][kk] = sum_j W[l][k][hd*64+j] * lW[l][hd*64+j][f], kk=hd*64+k
__global__ void k_prep_cmb(const float* __restrict__ W, const float* __restrict__ lW,
                           u16* __restrict__ CT) {
    int i = blockIdx.x * 256 + threadIdx.x;
    if (i >= 2 * 64 * 256) return;
    int l = i >> 14, rem = i & 16383;
    int f = rem >> 8, kk = rem & 255;
    int hd = kk >> 6, k = kk & 63;
    float s = 0.f;
    for (int j = 0; j < 64; ++j)
        s += W[(size_t)l * 16384 + k * 256 + hd * 64 + j] *
             lW[(size_t)l * 16384 + (hd * 64 + j) * 64 + f];
    CT[(size_t)l * 16384 + f * 256 + kk] = f2bf(s);
}

// cb[l][f] = sum_j gb[l][j]*lW[l][j][f] + lb[l][f]
__global__ void k_prep_cb(const float* __restrict__ gb, const float* __restrict__ lW,
                          const float* __restrict__ lb, float* __restrict__ cb) {
    int i = blockIdx.x * 256 + threadIdx.x;
    if (i >= 2 * 64) return;
    int l = i >> 6, f = i & 63;
    float s = lb[l * 64 + f];
    for (int j = 0; j < 256; ++j)
        s += gb[l * 256 + j] * lW[(size_t)l * 16384 + j * 64 + f];
    cb[l * 64 + f] = s;
}

// f32 -> bf16 bulk convert (float4 -> ushort4)
__global__ void k_f2bf4(const float* __restrict__ src, u16* __restrict__ dst, int n4) {
    int i = blockIdx.x * 256 + threadIdx.x;
    if (i >= n4) return;
    float4 f = ((const float4*)src)[i];
    ((ushort4*)dst)[i] = f4tobf(f);
}

// batched gather over all TT snapshots: dst[t][row][base..base+63] = x[t][clf[row]]
__global__ void k_gather(const u16* __restrict__ x, const int* __restrict__ clf,
                         u16* __restrict__ dst) {
    int i = blockIdx.x * 256 + threadIdx.x;
    if (i >= TT * NC * 16) return;
    int t = i / (NC * 16), rem = i % (NC * 16);
    int row = rem >> 4, c4 = rem & 15;
    int node = clf[row];
    ushort4 u = ((const ushort4*)(x + (size_t)t * NN * 64))[(size_t)node * 16 + c4];
    *(ushort4*)&dst[((size_t)t * NC + row) * 128 + c4 * 4] = u;
}

// ---------------- al/ar: x[M,64] dot was/wad[64][4] (M rows, batched) --------
__global__ __launch_bounds__(256) void k_alar_x(const u16* __restrict__ xb,
                                                const float* __restrict__ was,
                                                const float* __restrict__ wad,
                                                float* __restrict__ al,
                                                float* __restrict__ ar) {
    int lane = threadIdx.x & 63;
    int n = blockIdx.x * 16 + (threadIdx.x >> 6) * 4 + (lane >> 4);
    int q = lane & 15;
    ushort4 u = *(const ushort4*)&xb[(size_t)n * 64 + q * 4];
    float ps[4] = {0.f, 0.f, 0.f, 0.f};
    float pd[4] = {0.f, 0.f, 0.f, 0.f};
#pragma unroll
    for (int d = 0; d < 4; ++d) {
        u16 uv = (d == 0) ? u.x : (d == 1) ? u.y : (d == 2) ? u.z : u.w;
        float xv = bf2f(uv);
        int k = q * 4 + d;
        float4 w4 = *(const float4*)&was[k * 4];
        float4 d4 = *(const float4*)&wad[k * 4];
        ps[0] += xv * w4.x; ps[1] += xv * w4.y;
        ps[2] += xv * w4.z; ps[3] += xv * w4.w;
        pd[0] += xv * d4.x; pd[1] += xv * d4.y;
        pd[2] += xv * d4.z; pd[3] += xv * d4.w;
    }
#pragma unroll
    for (int o = 1; o < 16; o <<= 1) {
#pragma unroll
        for (int hd = 0; hd < 4; ++hd) {
            ps[hd] += __shfl_xor(ps[hd], o, 64);
            pd[hd] += __shfl_xor(pd[hd], o, 64);
        }
    }
    if (q == 0) {
        *(float4*)&al[n * 4] = make_float4(ps[0], ps[1], ps[2], ps[3]);
        *(float4*)&ar[n * 4] = make_float4(pd[0], pd[1], pd[2], pd[3]);
    }
}

// ---------------- attention aggregation, batched over TT snapshots ----------
__global__ __launch_bounds__(256) void k_agg_x(const int* __restrict__ off,
                                               const int* __restrict__ csr,
                                               const float* __restrict__ al,
                                               const float* __restrict__ ar,
                                               const u16* __restrict__ xb,
                                               u16* __restrict__ xagg) {
    const int bpt = NN / 4;      // blocks per snapshot
    int lane = threadIdx.x & 63;
    int t = blockIdx.x / bpt;
    int n = (blockIdx.x % bpt) * 4 + (threadIdx.x >> 6);
    const int* offp = off + (size_t)t * (NN + 1);
    const int* csrp = csr + (size_t)t * ET;
    const float* alp = al + (size_t)t * NN * 4;
    const u16* xbp = xb + (size_t)t * NN * 64;
    u16* xap = xagg + (size_t)t * NN * 256;
    int hh = lane & 3;
    int hf = lane >> 5;          // 0 = even edge of round, 1 = odd edge
    int kd = lane & 31;          // dim-pair index: dims 2kd, 2kd+1
    float ar_hh = ar[(size_t)t * NN * 4 + n * 4 + hh];
    int beg = offp[n], end = offp[n + 1];
    float den[4]  = {0.f, 0.f, 0.f, 0.f};
    float accL[4] = {0.f, 0.f, 0.f, 0.f};
    float accH[4] = {0.f, 0.f, 0.f, 0.f};

    for (int cbase = beg; cbase < end; cbase += 64) {
        int cnt = min(64, end - cbase);
        int sidx = csrp[cbase + ((lane < cnt) ? lane : 0)];
        int nbat = (cnt + 15) >> 4;
        float pb[4];
#pragma unroll
        for (int b = 0; b < 4; ++b) {
            if (b < nbat) {
                int jj = b * 16 + (lane >> 2);
                int sj = __shfl(sidx, (jj < cnt) ? jj : 0, 64);
                pb[b] = expf(lrelu(alp[sj * 4 + hh] + ar_hh));
            } else {
                pb[b] = 0.f;
            }
        }
        int R = (cnt + 1) >> 1;   // rounds of 2 edges

#define LDX(r, dstv)                                                         \
        {                                                                    \
            int jj_ = (r) * 2 + hf;                                          \
            int ss_ = __shfl(sidx, (jj_ < cnt) ? jj_ : 0, 64);               \
            dstv = *(const unsigned*)&xbp[(size_t)ss_ * 64 + kd * 2];        \
        }
#define CONS(r, cv)                                                         \
        {                                                                    \
            int je_ = (r) * 2 + hf;                                          \
            int b_ = ((r) >> 3) & 3;                                         \
            float pbb_ = (b_ == 0) ? pb[0] : (b_ == 1) ? pb[1]               \
                        : (b_ == 2) ? pb[2] : pb[3];                         \
            float xlo_ = bf2f((u16)((cv) & 0xffffu));                        \
            float xhi_ = bf2f((u16)((cv) >> 16));                            \
            _Pragma("unroll")                                                \
            for (int hd_ = 0; hd_ < 4; ++hd_) {                              \
                float p_ = __shfl(pbb_, ((je_ & 15) << 2) | hd_, 64);        \
                p_ = (je_ < cnt) ? p_ : 0.f;                                 \
                accL[hd_] += p_ * xlo_;                                      \
                accH[hd_] += p_ * xhi_;                                      \
                den[hd_]  += p_;                                             \
            }                                                                \
        }

        unsigned c0, c1, c2, c3;
        LDX(0, c0); LDX(1, c1); LDX(2, c2); LDX(3, c3);
        for (int g = 0; g < R; g += 4) {
            unsigned n0 = 0, n1 = 0, n2 = 0, n3 = 0;
            if (g + 4 < R) {          // wave-uniform
                LDX(g + 4, n0); LDX(g + 5, n1); LDX(g + 6, n2); LDX(g + 7, n3);
            }
            CONS(g + 0, c0);
            if (g + 1 < R) CONS(g + 1, c1);
            if (g + 2 < R) CONS(g + 2, c2);
            if (g + 3 < R) CONS(g + 3, c3);
            c0 = n0; c1 = n1; c2 = n2; c3 = n3;
        }
#undef LDX
#undef CONS
    }
    // merge even/odd halves
#pragma unroll
    for (int hd = 0; hd < 4; ++hd) {
        accL[hd] += __shfl_xor(accL[hd], 32, 64);
        accH[hd] += __shfl_xor(accH[hd], 32, 64);
        den[hd]  += __shfl_xor(den[hd], 32, 64);
    }
    if (hf == 0) {
#pragma unroll
        for (int hd = 0; hd < 4; ++hd) {
            float inv = 1.f / (den[hd] + 1e-16f);
            unsigned w = (unsigned)f2bf(accL[hd] * inv) |
                         ((unsigned)f2bf(accH[hd] * inv) << 16);
            *(unsigned*)&xap[(size_t)n * 256 + hd * 64 + kd * 2] = w;
        }
    }
}

// out[M,64](bf16) = relu(A[M,256](bf16) @ C[256,64] + cb)  -- MFMA 16x16x32
// Optional fused alar for the output rows (pre-bf16-rounding f32 values).
__global__ __launch_bounds__(256) void k_gemm_cmb(const u16* __restrict__ A,
                                                  const u16* __restrict__ CT,
                                                  const float* __restrict__ cb,
                                                  u16* __restrict__ out, int M,
                                                  const float* __restrict__ was2,
                                                  const float* __restrict__ wad2,
                                                  float* __restrict__ al1,
                                                  float* __restrict__ ar1) {
    int lane = threadIdx.x & 63;
    int wid = threadIdx.x >> 6;
    int g = lane >> 4, c = lane & 15;
    int r0 = blockIdx.x * 64 + wid * 16;
    int arow = r0 + c; if (arow > M - 1) arow = M - 1;
    const u16* aptr = A + (size_t)arow * 256 + g * 8;
    const u16* bptr = CT + (size_t)c * 256 + g * 8;
    f32x4 acc[4];
#pragma unroll
    for (int t = 0; t < 4; ++t) acc[t] = (f32x4){0.f, 0.f, 0.f, 0.f};
#pragma unroll
    for (int ks = 0; ks < 8; ++ks) {
        bf16x8 af = *(const bf16x8*)(aptr + ks * 32);
#pragma unroll
        for (int t = 0; t < 4; ++t) {
            bf16x8 bfr = *(const bf16x8*)(bptr + t * 16 * 256 + ks * 32);
            acc[t] = __builtin_amdgcn_mfma_f32_16x16x32_bf16(af, bfr, acc[t], 0, 0, 0);
        }
    }
    int orow0 = r0 + g * 4;
    float ps[4][4], pd[4][4];
#pragma unroll
    for (int j = 0; j < 4; ++j)
#pragma unroll
        for (int hd = 0; hd < 4; ++hd) { ps[j][hd] = 0.f; pd[j][hd] = 0.f; }
#pragma unroll
    for (int t = 0; t < 4; ++t) {
        int col = t * 16 + c;
        float bv = cb[col];
        float4 w4 = make_float4(0.f, 0.f, 0.f, 0.f), d4 = w4;
        if (al1) {
            w4 = *(const float4*)&was2[col * 4];
            d4 = *(const float4*)&wad2[col * 4];
        }
#pragma unroll
        for (int j = 0; j < 4; ++j) {
            int row = orow0 + j;
            float o = fmaxf(acc[t][j] + bv, 0.f);
            if (row < M) out[(size_t)row * 64 + col] = f2bf(o);
            if (al1) {
                ps[j][0] += o * w4.x; ps[j][1] += o * w4.y;
                ps[j][2] += o * w4.z; ps[j][3] += o * w4.w;
                pd[j][0] += o * d4.x; pd[j][1] += o * d4.y;
                pd[j][2] += o * d4.z; pd[j][3] += o * d4.w;
            }
        }
    }
    if (al1) {
#pragma unroll
        for (int o = 1; o < 16; o <<= 1) {
#pragma unroll
            for (int j = 0; j < 4; ++j) {
#pragma unroll
                for (int hd = 0; hd < 4; ++hd) {
                    ps[j][hd] += __shfl_xor(ps[j][hd], o, 64);
                    pd[j][hd] += __shfl_xor(pd[j][hd], o, 64);
                }
            }
        }
        if (c == 0) {
#pragma unroll
            for (int j = 0; j < 4; ++j) {
                int row = orow0 + j;
                if (row < M) {
                    *(float4*)&al1[row * 4] = make_float4(ps[j][0], ps[j][1], ps[j][2], ps[j][3]);
                    *(float4*)&ar1[row * 4] = make_float4(pd[j][0], pd[j][1], pd[j][2], pd[j][3]);
                }
            }
        }
    }
}

// gx[M][256] = seq2[M][128](bf16) @ Wi1^T (Wi1b [256][128] bf16)  -- MFMA
__global__ __launch_bounds__(256) void k_gemm_gx(const u16* __restrict__ A,
                                                 const u16* __restrict__ BT,
                                                 float* __restrict__ gxout, int M) {
    int lane = threadIdx.x & 63;
    int wid = threadIdx.x >> 6;
    int g = lane >> 4, c = lane & 15;
    int r0 = blockIdx.x * 64 + wid * 16;
    int arow = r0 + c; if (arow > M - 1) arow = M - 1;
    const u16* aptr = A + (size_t)arow * 128 + g * 8;
    f32x4 acc[16];
#pragma unroll
    for (int t = 0; t < 16; ++t) acc[t] = (f32x4){0.f, 0.f, 0.f, 0.f};
#pragma unroll
    for (int ks = 0; ks < 4; ++ks) {
        bf16x8 af = *(const bf16x8*)(aptr + ks * 32);
#pragma unroll
        for (int t = 0; t < 16; ++t) {
            bf16x8 bfr = *(const bf16x8*)(BT + (size_t)(t * 16 + c) * 128 + ks * 32 + g * 8);
            acc[t] = __builtin_amdgcn_mfma_f32_16x16x32_bf16(af, bfr, acc[t], 0, 0, 0);
        }
    }
#pragma unroll
    for (int t = 0; t < 16; ++t) {
#pragma unroll
        for (int j = 0; j < 4; ++j) {
            int row = r0 + g * 4 + j;
            if (row < M) gxout[(size_t)row * 256 + t * 16 + c] = acc[t][j];
        }
    }
}

// ---------------- fused LSTM (recurrent part only) + FC, 4 rows/wave ---------
__global__ __launch_bounds__(256) void k_lstm_fc(const float* __restrict__ gx,
                                                 const float* __restrict__ WhT1,
                                                 const float* __restrict__ bb1,
                                                 const float* __restrict__ WiT2,
                                                 const float* __restrict__ WhT2,
                                                 const float* __restrict__ bb2,
                                                 const float* __restrict__ fw1,
                                                 const float* __restrict__ fb1,
                                                 const float* __restrict__ fw2,
                                                 const float* __restrict__ fb2,
                                                 float* __restrict__ out) {
    __shared__ float xs[4][4][128];
    int w = threadIdx.x >> 6, lane = threadIdx.x & 63;
    int row0 = blockIdx.x * 16 + w * 4;
    float h1[4], c1[4], h2[4], c2[4];
#pragma unroll
    for (int r = 0; r < 4; ++r) { h1[r] = 0.f; c1[r] = 0.f; h2[r] = 0.f; c2[r] = 0.f; }
    float bi1 = bb1[lane], bf1 = bb1[64 + lane], bg1 = bb1[128 + lane], bo1 = bb1[192 + lane];
    float bi2 = bb2[lane], bf2v = bb2[64 + lane], bg2 = bb2[128 + lane], bo2 = bb2[192 + lane];

    for (int st = 0; st < TT; ++st) {
        int tsn = TT - 1 - st;   // outs[::-1]
        // ---- LSTM1: gates = gx + Wh1 @ h1 + b
#pragma unroll
        for (int r = 0; r < 4; ++r) xs[w][r][lane] = h1[r];
        __syncthreads();
        {
            const float* gxp = gx + (size_t)tsn * NC * 256;
            float ai[4], af[4], ag[4], ao[4];
#pragma unroll
            for (int r = 0; r < 4; ++r) {
                const float* gr = gxp + (size_t)(row0 + r) * 256;
                ai[r] = bi1 + gr[lane];
                af[r] = bf1 + gr[64 + lane];
                ag[r] = bg1 + gr[128 + lane];
                ao[r] = bo1 + gr[192 + lane];
            }
            for (int k = 0; k < 64; ++k) {
                const float* wr = &WhT1[k * 256];
                float wi = wr[lane], wf = wr[64 + lane], wg = wr[128 + lane], wo = wr[192 + lane];
#pragma unroll
                for (int r = 0; r < 4; ++r) {
                    float hv = xs[w][r][k];
                    ai[r] += hv * wi; af[r] += hv * wf;
                    ag[r] += hv * wg; ao[r] += hv * wo;
                }
            }
#pragma unroll
            for (int r = 0; r < 4; ++r) {
                c1[r] = sigm(af[r]) * c1[r] + sigm(ai[r]) * tanhf(ag[r]);
                h1[r] = sigm(ao[r]) * tanhf(c1[r]);
            }
        }
        __syncthreads();
        // ---- LSTM2: x = h1 (64), h = h2
#pragma unroll
        for (int r = 0; r < 4; ++r) {
            xs[w][r][lane]      = h1[r];
            xs[w][r][64 + lane] = h2[r];
        }
        __syncthreads();
        {
            float ai[4], af[4], ag[4], ao[4];
#pragma unroll
            for (int r = 0; r < 4; ++r) { ai[r] = bi2; af[r] = bf2v; ag[r] = bg2; ao[r] = bo2; }
            for (int k = 0; k < 64; ++k) {
                const float* wr = &WiT2[k * 256];
                float wi = wr[lane], wf = wr[64 + lane], wg = wr[128 + lane], wo = wr[192 + lane];
#pragma unroll
                for (int r = 0; r < 4; ++r) {
                    float xv = xs[w][r][k];
                    ai[r] += xv * wi; af[r] += xv * wf;
                    ag[r] += xv * wg; ao[r] += xv * wo;
                }
            }
            for (int k = 0; k < 64; ++k) {
                const float* wr = &WhT2[k * 256];
                float wi = wr[lane], wf = wr[64 + lane], wg = wr[128 + lane], wo = wr[192 + lane];
#pragma unroll
                for (int r = 0; r < 4; ++r) {
                    float hv = xs[w][r][64 + k];
                    ai[r] += hv * wi; af[r] += hv * wf;
                    ag[r] += hv * wg; ao[r] += hv * wo;
                }
            }
#pragma unroll
            for (int r = 0; r < 4; ++r) {
                c2[r] = sigm(af[r]) * c2[r] + sigm(ai[r]) * tanhf(ag[r]);
                h2[r] = sigm(ao[r]) * tanhf(c2[r]);
            }
        }
        __syncthreads();
    }
    // ---- FC head: z = [h1 | h2]
#pragma unroll
    for (int r = 0; r < 4; ++r) {
        xs[w][r][lane]      = h1[r];
        xs[w][r][64 + lane] = h2[r];
    }
    __syncthreads();
    float acc[4];
#pragma unroll
    for (int r = 0; r < 4; ++r) acc[r] = fb1[lane];
    for (int k = 0; k < 128; ++k) {
        float wv = fw1[k * 64 + lane];
#pragma unroll
        for (int r = 0; r < 4; ++r) acc[r] += xs[w][r][k] * wv;
    }
    float w20 = fw2[lane * 2], w21 = fw2[lane * 2 + 1];
#pragma unroll
    for (int r = 0; r < 4; ++r) {
        float rr = fmaxf(acc[r], 0.f);
        float t0 = rr * w20;
        float t1 = rr * w21;
#pragma unroll
        for (int o = 32; o >= 1; o >>= 1) {
            t0 += __shfl_xor(t0, o, 64);
            t1 += __shfl_xor(t1, o, 64);
        }
        if (lane == 0) {
            out[(row0 + r) * 2]     = fmaxf(t0 + fb2[0], 0.f);
            out[(row0 + r) * 2 + 1] = fmaxf(t1 + fb2[1], 0.f);
        }
    }
}

extern "C" void kernel_launch(void* const* d_in, const int* in_sizes, int n_in,
                              void* d_out, int out_size, void* d_ws, size_t ws_size,
                              hipStream_t stream) {
    const float* emb  = (const float*)d_in[0];
    const float* g1W  = (const float*)d_in[1];
    const float* g1as = (const float*)d_in[2];
    const float* g1ad = (const float*)d_in[3];
    const float* g1b  = (const float*)d_in[4];
    const float* l1W  = (const float*)d_in[5];
    const float* l1b  = (const float*)d_in[6];
    const float* g2W  = (const float*)d_in[7];
    const float* g2as = (const float*)d_in[8];
    const float* g2ad = (const float*)d_in[9];
    const float* g2b  = (const float*)d_in[10];
    const float* l2W  = (const float*)d_in[11];
    const float* l2b  = (const float*)d_in[12];
    const float* Wi1  = (const float*)d_in[13];
    const float* Wh1  = (const float*)d_in[14];
    const float* b1   = (const float*)d_in[15];
    const float* Wi2  = (const float*)d_in[16];
    const float* Wh2  = (const float*)d_in[17];
    const float* b2   = (const float*)d_in[18];
    const float* fc1W = (const float*)d_in[19];
    const float* fc1b = (const float*)d_in[20];
    const float* fc2W = (const float*)d_in[21];
    const float* fc2b = (const float*)d_in[22];
    const int* edges = (const int*)d_in[23];
    const int* clf   = (const int*)d_in[27];

    char* ws = (char*)d_ws;
    size_t woff = 0;
    auto alloc = [&](size_t bytes) -> void* {
        void* p = ws + woff;
        woff += (bytes + 255) & ~(size_t)255;
        return p;
    };
    int* csr_off  = (int*)alloc((size_t)TT * (NN + 1) * 4);
    int* csr_fil  = (int*)alloc((size_t)TT * NN * 4);
    int* csr_src  = (int*)alloc((size_t)TT * ET * 4);
    int* scan_sum = (int*)alloc((size_t)TT * NCH * 4);
    int* scan_bas = (int*)alloc((size_t)TT * NCH * 4);
    u16* embb     = (u16*)alloc((size_t)TT * NN * 64 * 2);
    u16* xbuf5    = (u16*)alloc((size_t)TT * NN * 64 * 2);    // layer outputs, all t
    u16* xaggb    = (u16*)alloc((size_t)TT * NN * 256 * 2);   // agg outputs, all t
    float* al0    = (float*)alloc((size_t)TT * NN * 4 * 4);
    float* ar0    = (float*)alloc((size_t)TT * NN * 4 * 4);
    float* al1    = (float*)alloc((size_t)TT * NN * 4 * 4);
    float* ar1    = (float*)alloc((size_t)TT * NN * 4 * 4);
    u16* seq2     = (u16*)alloc((size_t)TT * NC * 128 * 2);   // [t][row][e1|e2] bf16
    // gx aliases xaggb: xaggb's last read (s=1 layer-1 GEMM) precedes gemm_gx.
    // gx needs TT*NC*256*4 = 42 MB <= xaggb's 128 MB region.
    float* gxb    = (float*)xaggb;
    float* WhT1   = (float*)alloc(64 * 256 * 4);
    float* WiT2   = (float*)alloc(64 * 256 * 4);
    float* WhT2   = (float*)alloc(64 * 256 * 4);
    u16* wi1b     = (u16*)alloc((size_t)256 * 128 * 2);       // Wi1 bf16 [256][128]
    u16* CT1      = (u16*)alloc((size_t)2 * 64 * 256 * 2);    // [L][64][256] bf16
    u16* CT2      = (u16*)alloc((size_t)2 * 64 * 256 * 2);
    float* cb1    = (float*)alloc((size_t)2 * 64 * 4);
    float* cb2    = (float*)alloc((size_t)2 * 64 * 4);
    float* wasb1  = (float*)alloc((size_t)2 * 64 * 4 * 4);    // [L][64][4]
    float* wadb1  = (float*)alloc((size_t)2 * 64 * 4 * 4);
    float* wasb2  = (float*)alloc((size_t)2 * 64 * 4 * 4);
    float* wadb2  = (float*)alloc((size_t)2 * 64 * 4 * 4);

    // CSR build (per snapshot, includes self-loops)
    k_fill1<<<(TT * NN + 255) / 256, 256, 0, stream>>>(csr_fil, TT * NN);
    k_count<<<(TT * EE + 255) / 256, 256, 0, stream>>>(edges, csr_fil);
    k_scan1<<<TT * NCH, 256, 0, stream>>>(csr_fil, scan_sum);
    k_scan2<<<TT, 256, 0, stream>>>(scan_sum, scan_bas, csr_off);
    k_scan3<<<TT * NCH, 256, 0, stream>>>(csr_fil, scan_bas, csr_off);
    k_csrfill<<<(TT * ET + 255) / 256, 256, 0, stream>>>(edges, csr_fil, csr_src);

    // weight preps
    k_transpose<<<(256 * 64 + 255) / 256, 256, 0, stream>>>(Wh1, WhT1, 256, 64);
    k_transpose<<<(256 * 64 + 255) / 256, 256, 0, stream>>>(Wi2, WiT2, 256, 64);
    k_transpose<<<(256 * 64 + 255) / 256, 256, 0, stream>>>(Wh2, WhT2, 256, 64);
    k_prep_wi1<<<(256 * 128 + 255) / 256, 256, 0, stream>>>(Wi1, wi1b);
    k_prep_was<<<2, 256, 0, stream>>>(g1W, g1as, g1ad, wasb1, wadb1);
    k_prep_was<<<2, 256, 0, stream>>>(g2W, g2as, g2ad, wasb2, wadb2);
    k_prep_cmb<<<(2 * 64 * 256 + 255) / 256, 256, 0, stream>>>(g1W, l1W, CT1);
    k_prep_cmb<<<(2 * 64 * 256 + 255) / 256, 256, 0, stream>>>(g2W, l2W, CT2);
    k_prep_cb<<<1, 256, 0, stream>>>(g1b, l1W, l1b, cb1);
    k_prep_cb<<<1, 256, 0, stream>>>(g2b, l2W, l2b, cb2);
    // emb -> bf16
    k_f2bf4<<<(TT * NN * 16 + 255) / 256, 256, 0, stream>>>(emb, embb, TT * NN * 16);

    const int MB = TT * NN;  // batched row count
    for (int s = 0; s < 2; ++s) {
        const float* was = s ? wasb2 : wasb1;
        const float* wad = s ? wadb2 : wadb1;
        const u16* CT    = s ? CT2 : CT1;
        const float* cbp = s ? cb2 : cb1;
        // layer 0, all snapshots in one pass
        k_alar_x<<<MB / 16, 256, 0, stream>>>(
            embb, was + 0 * 256, wad + 0 * 256, al0, ar0);
        k_agg_x<<<TT * (NN / 4), 256, 0, stream>>>(
            csr_off, csr_src, al0, ar0, embb, xaggb);
        k_gemm_cmb<<<(MB + 63) / 64, 256, 0, stream>>>(
            xaggb, CT + (size_t)0 * 16384, cbp + 0 * 64, xbuf5, MB,
            was + 1 * 256, wad + 1 * 256, al1, ar1);
        // layer 1, all snapshots in one pass (al/ar fused from layer-0 GEMM)
        k_agg_x<<<TT * (NN / 4), 256, 0, stream>>>(
            csr_off, csr_src, al1, ar1, xbuf5, xaggb);
        k_gemm_cmb<<<(MB + 63) / 64, 256, 0, stream>>>(
            xaggb, CT + (size_t)1 * 16384, cbp + 1 * 64, xbuf5, MB,
            nullptr, nullptr, nullptr, nullptr);
        // batched gather: seq2[t][row][s*64..] = xbuf5[t][clf[row]]
        k_gather<<<(TT * NC * 16 + 255) / 256, 256, 0, stream>>>(
            xbuf5, clf, seq2 + s * 64);
    }

    // LSTM1 x-gates for all steps: gx = seq2 @ Wi1^T  (M = TT*NC)
    // (gxb aliases xaggb; all xaggb reads completed above)
    k_gemm_gx<<<(TT * NC + 63) / 64, 256, 0, stream>>>(seq2, wi1b, gxb, TT * NC);

    // fused recurrent LSTM + FC, 4 rows/wave (2 waves/SIMD)
    k_lstm_fc<<<NC / 16, 256, 0, stream>>>(
        gxb, WhT1, b1, WiT2, WhT2, b2,
        fc1W, fc1b, fc2W, fc2b, (float*)d_out);
}